// Round 10
// baseline (2078.626 us; speedup 1.0000x reference)
//
#include <hip/hip_runtime.h>

// ---------------------------------------------------------------------------
// 4-layer transformer decoder, bf16 MFMA implementation (round 10).
// gemm128 = r8 proven structure (128x128, BK=32, 2-buf, syncthreads, 4/CU)
// with A-operand DIRECT-TO-REGISTER (16B coalesced global loads, ping-pong
// prefetch) -- LDS stages only B (16 KB). Halves LDS traffic per step.
// Out-proj: split-K2 + ln_red2. caQ+caKV dual-job. attn: 128-thr + tile-skip.
// ---------------------------------------------------------------------------

typedef __attribute__((ext_vector_type(4))) float f32x4;
typedef __attribute__((ext_vector_type(8))) short bf16x8;
typedef __attribute__((ext_vector_type(4))) unsigned short u16x4;
typedef __attribute__((ext_vector_type(4))) unsigned int   u32x4;

__device__ __forceinline__ unsigned short f2bf(float f) {
    unsigned int u = __builtin_bit_cast(unsigned int, f);
    u += 0x7fffu + ((u >> 16) & 1u);   // RNE
    return (unsigned short)(u >> 16);
}

__device__ __forceinline__ void gll16(const unsigned short* g, unsigned short* l) {
    auto* gp = reinterpret_cast<const __attribute__((address_space(1))) unsigned int*>(
        reinterpret_cast<uintptr_t>(g));
    auto* lp = reinterpret_cast<__attribute__((address_space(3))) unsigned int*>(
        reinterpret_cast<uintptr_t>(l));
    __builtin_amdgcn_global_load_lds(gp, lp, 16, 0, 0);
}

// ---------------------------------------------------------------------------
// Shared 128x128 GEMM body. B in LDS (2-buf, slot-XOR swizzle, gll16);
// A fragments direct global->VGPR, ping-pong prefetched (static indexing).
// mode 0: bf16(acc+bias)  1: bf16(relu(acc+bias))  3: raw f32 -> po
// ---------------------------------------------------------------------------
__device__ __forceinline__ void gemm_body(
    const unsigned short* __restrict__ A,
    const unsigned short* __restrict__ Bw,
    const float* __restrict__ bias,
    unsigned short* __restrict__ outb,
    float* __restrict__ po,
    int N, int lda, int klen, int mode,
    int m0, int n0, int kz,
    unsigned short (*Bl)[128 * 32])
{
    const int tid  = threadIdx.x;
    const int lane = tid & 63;
    const int w    = tid >> 6;
    const int wr   = (w >> 1) * 64;
    const int wc   = (w & 1) * 64;
    const int l15  = lane & 15;
    const int l4   = lane >> 4;

    // B staging: wave w covers rows w*16..w*16+15 (+64 for j=1); lane's 16B
    // chunk lands at LDS slot lane&3; global col pre-swizzled slot^((row>>1)&3).
    const int srow = w * 16 + (lane >> 2);
    const int scol = ((lane & 3) ^ ((srow >> 1) & 3)) * 8;
    const unsigned short* bg = Bw + (size_t)(n0 + srow) * lda + kz + scol;
    const size_t jstep = (size_t)64 * lda;
    const int lbase = (w * 16) * 32;

    // B fragment LDS offsets: row r, k-chunk l4 at slot l4^((r>>1)&3)
    int boff[4];
    #pragma unroll
    for (int i = 0; i < 4; ++i) {
        const int rb = wc + i * 16 + l15;
        boff[i] = rb * 32 + ((l4 ^ ((rb >> 1) & 3)) * 8);
    }

    // A direct: lane's frag i for tile t = 16B at ab + i*16*lda + t*32
    const unsigned short* ab = A + (size_t)(m0 + wr + l15) * lda + kz + l4 * 8;
    const size_t astep = (size_t)16 * lda;

    f32x4 acc[4][4];
    #pragma unroll
    for (int mi = 0; mi < 4; ++mi)
        #pragma unroll
        for (int ni = 0; ni < 4; ++ni)
            acc[mi][ni] = (f32x4){0.f, 0.f, 0.f, 0.f};

    bf16x8 afA[4], afB[4];
    // prologue: A frags for tile 0; B tile 0 -> buf 0
    #pragma unroll
    for (int i = 0; i < 4; ++i)
        afA[i] = *reinterpret_cast<const bf16x8*>(ab + (size_t)i * astep);
    #pragma unroll
    for (int j = 0; j < 2; ++j)
        gll16(bg + j * jstep, &Bl[0][lbase + j * 64 * 32]);
    __syncthreads();

    const int nt = klen >> 5;           // always even (K multiples of 64)
    for (int t = 0; t < nt; t += 2) {
        // ---- even tile t (buf 0), prefetch t+1 (buf 1) ----
        if (t + 1 < nt) {
            #pragma unroll
            for (int j = 0; j < 2; ++j)
                gll16(bg + (t + 1) * 32 + j * jstep, &Bl[1][lbase + j * 64 * 32]);
            #pragma unroll
            for (int i = 0; i < 4; ++i)
                afB[i] = *reinterpret_cast<const bf16x8*>(ab + (t + 1) * 32 + (size_t)i * astep);
        }
        {
            const unsigned short* bc = &Bl[0][0];
            bf16x8 bf[4];
            #pragma unroll
            for (int i = 0; i < 4; ++i) bf[i] = *reinterpret_cast<const bf16x8*>(&bc[boff[i]]);
            #pragma unroll
            for (int mi = 0; mi < 4; ++mi)
                #pragma unroll
                for (int ni = 0; ni < 4; ++ni)
                    acc[mi][ni] = __builtin_amdgcn_mfma_f32_16x16x32_bf16(afA[mi], bf[ni], acc[mi][ni], 0, 0, 0);
        }
        __syncthreads();
        // ---- odd tile t+1 (buf 1), prefetch t+2 (buf 0) ----
        if (t + 1 < nt) {
            if (t + 2 < nt) {
                #pragma unroll
                for (int j = 0; j < 2; ++j)
                    gll16(bg + (t + 2) * 32 + j * jstep, &Bl[0][lbase + j * 64 * 32]);
                #pragma unroll
                for (int i = 0; i < 4; ++i)
                    afA[i] = *reinterpret_cast<const bf16x8*>(ab + (t + 2) * 32 + (size_t)i * astep);
            }
            const unsigned short* bc = &Bl[1][0];
            bf16x8 bf[4];
            #pragma unroll
            for (int i = 0; i < 4; ++i) bf[i] = *reinterpret_cast<const bf16x8*>(&bc[boff[i]]);
            #pragma unroll
            for (int mi = 0; mi < 4; ++mi)
                #pragma unroll
                for (int ni = 0; ni < 4; ++ni)
                    acc[mi][ni] = __builtin_amdgcn_mfma_f32_16x16x32_bf16(afB[mi], bf[ni], acc[mi][ni], 0, 0, 0);
            __syncthreads();
        }
    }

    // epilogue: C/D layout col = lane&15, row = (lane>>4)*4 + r
    #pragma unroll
    for (int mi = 0; mi < 4; ++mi) {
        #pragma unroll
        for (int ni = 0; ni < 4; ++ni) {
            const int col = n0 + wc + ni * 16 + l15;
            const float bs = (mode == 3) ? 0.f : bias[col];
            #pragma unroll
            for (int r = 0; r < 4; ++r) {
                const int row = m0 + wr + mi * 16 + l4 * 4 + r;
                const float val = acc[mi][ni][r] + bs;
                if (mode == 0)      outb[(size_t)row * N + col] = f2bf(val);
                else if (mode == 1) outb[(size_t)row * N + col] = f2bf(fmaxf(val, 0.f));
                else                po[(size_t)row * N + col] = val;
            }
        }
    }
}

// gemm128: XCD band swizzle (gy == 32, nwg % 8 == 0); split-K via blockIdx.z.
__global__ __launch_bounds__(256, 4) void gemm128(
    const unsigned short* __restrict__ A,
    const unsigned short* __restrict__ Bw,
    const float* __restrict__ bias,
    unsigned short* __restrict__ outb,
    float* __restrict__ outf0,
    float* __restrict__ outf1,
    int N, int lda, int klen, int mode)
{
    __shared__ unsigned short Bl[2][128 * 32];
    const int gx   = gridDim.x;
    const int orig = blockIdx.y * gx + blockIdx.x;
    const int xcd  = orig & 7;
    const int lin  = orig >> 3;
    const int m0   = (xcd * 4 + (lin & 3)) * 128;
    const int n0   = (lin >> 2) * 128;
    const int kz   = blockIdx.z * klen;
    float* po = (blockIdx.z == 0) ? outf0 : outf1;
    gemm_body(A, Bw, bias, outb, po, N, lda, klen, mode, m0, n0, kz, Bl);
}

// gemm128_ca: dual-job dispatch (caQ N=1024 | caKV N=2048), both mode 0.
__global__ __launch_bounds__(256, 4) void gemm128_ca(
    const unsigned short* __restrict__ A0, const unsigned short* __restrict__ A1,
    const unsigned short* __restrict__ B0, const unsigned short* __restrict__ B1,
    const float* __restrict__ bias0, const float* __restrict__ bias1,
    unsigned short* __restrict__ out0, unsigned short* __restrict__ out1,
    int lda, int klen)
{
    __shared__ unsigned short Bl[2][128 * 32];
    const int grp = (blockIdx.x >= 8);
    const int bx  = blockIdx.x - (grp ? 8 : 0);
    const int lgx = grp ? 16 : 8;
    const int orig = blockIdx.y * lgx + bx;
    const int xcd  = orig & 7;
    const int lin  = orig >> 3;
    const int m0   = (xcd * 4 + (lin & 3)) * 128;
    const int n0   = (lin >> 2) * 128;
    gemm_body(grp ? A1 : A0, grp ? B1 : B0, grp ? bias1 : bias0,
              grp ? out1 : out0, nullptr, grp ? 2048 : 1024, lda, klen, 0,
              m0, n0, 0, Bl);
}

// ---------------------------------------------------------------------------
// Fused attention: 128-thread blocks (2 waves), grid 512 = (n,h,thalf).
// Causal: wave-uniform tile-skip in QK and PV.
// ---------------------------------------------------------------------------
__global__ __launch_bounds__(128) void attn_fused(
    const unsigned short* __restrict__ Q, int qs,
    const unsigned short* __restrict__ Kb, int ks_,
    const unsigned short* __restrict__ Vb, int vs,
    unsigned short* __restrict__ O,
    int causal)
{
    __shared__ unsigned short Kl[8][256][8];        // 32 KB
    __shared__ unsigned short Vt[32][64][8];        // 32 KB
    __shared__ unsigned short Pl[2][32][16][8];     // 16 KB
    const int tid   = threadIdx.x;
    const int lane  = tid & 63;
    const int w     = tid >> 6;
    const int bxi   = blockIdx.x;
    const int n     = bxi >> 5;
    const int h     = (bxi >> 1) & 15;
    const int thalf = bxi & 1;
    const int l15   = lane & 15;
    const int l4    = lane >> 4;
    const size_t hoff = (size_t)h * 64;

    #pragma unroll
    for (int i = 0; i < 16; ++i) {
        const int e = i * 128 + tid;
        const int s = e >> 3;
        const int c = e & 7;
        u32x4 kv = *reinterpret_cast<const u32x4*>(&Kb[((size_t)s * 16 + n) * ks_ + hoff + c * 8]);
        *reinterpret_cast<u32x4*>(&Kl[c][s][0]) = kv;
        u32x4 vv = *reinterpret_cast<const u32x4*>(&Vb[((size_t)s * 16 + n) * vs + hoff + c * 8]);
        const unsigned short* ve = reinterpret_cast<const unsigned short*>(&vv);
        #pragma unroll
        for (int j = 0; j < 8; ++j)
            Vt[s >> 3][c * 8 + j][s & 7] = ve[j];
    }
    __syncthreads();

    for (int ch = 0; ch < 4; ++ch) {
        const int t0 = thalf * 128 + w * 64 + ch * 16;
        bf16x8 qa[2];
        #pragma unroll
        for (int ks = 0; ks < 2; ++ks)
            qa[ks] = *reinterpret_cast<const bf16x8*>(
                &Q[((size_t)(t0 + l15) * 16 + n) * qs + hoff + ks * 32 + l4 * 8]);

        f32x4 sc[16];
        #pragma unroll
        for (int st = 0; st < 16; ++st) {
            if (causal && st * 16 > t0 + 15) {
                sc[st] = (f32x4){-1e9f, -1e9f, -1e9f, -1e9f};
                continue;
            }
            f32x4 a = (f32x4){0.f, 0.f, 0.f, 0.f};
            #pragma unroll
            for (int ks = 0; ks < 2; ++ks) {
                bf16x8 kf = *reinterpret_cast<const bf16x8*>(&Kl[ks * 4 + l4][st * 16 + l15][0]);
                a = __builtin_amdgcn_mfma_f32_16x16x32_bf16(qa[ks], kf, a, 0, 0, 0);
            }
            sc[st] = a;
        }
        if (causal) {
            #pragma unroll
            for (int st = 0; st < 16; ++st) {
                const int sg = st * 16 + l15;
                #pragma unroll
                for (int r = 0; r < 4; ++r) {
                    const int tg = t0 + l4 * 4 + r;
                    if (sg > tg) sc[st][r] = -1e9f;
                }
            }
        }
        #pragma unroll
        for (int r = 0; r < 4; ++r) {
            float mx = -3.0e38f;
            #pragma unroll
            for (int st = 0; st < 16; ++st) mx = fmaxf(mx, sc[st][r]);
            #pragma unroll
            for (int dd = 1; dd < 16; dd <<= 1) mx = fmaxf(mx, __shfl_xor(mx, dd, 64));
            float sum = 0.f;
            #pragma unroll
            for (int st = 0; st < 16; ++st) {
                const float e = __expf(sc[st][r] - mx);
                sc[st][r] = e;
                sum += e;
            }
            #pragma unroll
            for (int dd = 1; dd < 16; dd <<= 1) sum += __shfl_xor(sum, dd, 64);
            const float inv = 1.f / sum;
            const int rl = l4 * 4 + r;
            #pragma unroll
            for (int st = 0; st < 16; ++st) {
                const int sg = st * 16 + l15;
                Pl[w][sg >> 3][rl][sg & 7] = f2bf(sc[st][r] * inv);
            }
        }
        f32x4 oacc[4];
        #pragma unroll
        for (int dt = 0; dt < 4; ++dt) oacc[dt] = (f32x4){0.f, 0.f, 0.f, 0.f};
        #pragma unroll
        for (int kt = 0; kt < 8; ++kt) {
            if (causal && kt * 32 > t0 + 15) continue;
            bf16x8 pa = *reinterpret_cast<const bf16x8*>(&Pl[w][kt * 4 + l4][l15][0]);
            #pragma unroll
            for (int dt = 0; dt < 4; ++dt) {
                bf16x8 vf = *reinterpret_cast<const bf16x8*>(&Vt[kt * 4 + l4][dt * 16 + l15][0]);
                oacc[dt] = __builtin_amdgcn_mfma_f32_16x16x32_bf16(pa, vf, oacc[dt], 0, 0, 0);
            }
        }
        #pragma unroll
        for (int dt = 0; dt < 4; ++dt)
            #pragma unroll
            for (int r = 0; r < 4; ++r)
                O[((size_t)(t0 + l4 * 4 + r) * 16 + n) * 1024 + hoff + dt * 16 + l15] = f2bf(oacc[dt][r]);
    }
}

// ---------------------------------------------------------------------------
// LayerNorm over D=1024, one wave per row (plain and fused-reduce variants)
// ---------------------------------------------------------------------------
__device__ __forceinline__ void ln_body(
    f32x4 (&v)[4], int row, int lane,
    const float* __restrict__ g, const float* __restrict__ b,
    float* __restrict__ xf, unsigned short* __restrict__ xb)
{
    float s = 0.f;
    #pragma unroll
    for (int i = 0; i < 4; ++i) s += v[i][0] + v[i][1] + v[i][2] + v[i][3];
    #pragma unroll
    for (int dd = 1; dd < 64; dd <<= 1) s += __shfl_xor(s, dd, 64);
    const float mu = s * (1.f / 1024.f);
    float q = 0.f;
    #pragma unroll
    for (int i = 0; i < 4; ++i)
        #pragma unroll
        for (int j = 0; j < 4; ++j) { const float d0 = v[i][j] - mu; q += d0 * d0; }
    #pragma unroll
    for (int dd = 1; dd < 64; dd <<= 1) q += __shfl_xor(q, dd, 64);
    const float rstd = rsqrtf(q * (1.f / 1024.f) + 1e-5f);
    #pragma unroll
    for (int i = 0; i < 4; ++i) {
        const int col = i * 256 + lane * 4;
        f32x4 gg = *reinterpret_cast<const f32x4*>(&g[col]);
        f32x4 bb = *reinterpret_cast<const f32x4*>(&b[col]);
        f32x4 y;
        #pragma unroll
        for (int j = 0; j < 4; ++j) y[j] = (v[i][j] - mu) * rstd * gg[j] + bb[j];
        if (xf) *reinterpret_cast<f32x4*>(&xf[(size_t)row * 1024 + col]) = y;
        if (xb) {
            u16x4 pk;
            #pragma unroll
            for (int j = 0; j < 4; ++j) pk[j] = f2bf(y[j]);
            *reinterpret_cast<u16x4*>(&xb[(size_t)row * 1024 + col]) = pk;
        }
    }
}

__global__ __launch_bounds__(256) void ln_kernel(
    const float* __restrict__ z, const float* __restrict__ g, const float* __restrict__ b,
    float* __restrict__ xf, unsigned short* __restrict__ xb)
{
    const int row  = blockIdx.x * 4 + (threadIdx.x >> 6);
    const int lane = threadIdx.x & 63;
    f32x4 v[4];
    #pragma unroll
    for (int i = 0; i < 4; ++i)
        v[i] = *reinterpret_cast<const f32x4*>(&z[(size_t)row * 1024 + i * 256 + lane * 4]);
    ln_body(v, row, lane, g, b, xf, xb);
}

// z = p0 + p1 + bias + resid, then LN. resid may alias xf (row-local).
__global__ __launch_bounds__(256) void ln_red2(
    const float* __restrict__ p0, const float* __restrict__ p1,
    const float* __restrict__ bias, const float* __restrict__ resid,
    const float* __restrict__ g, const float* __restrict__ b,
    float* __restrict__ xf, unsigned short* __restrict__ xb)
{
    const int row  = blockIdx.x * 4 + (threadIdx.x >> 6);
    const int lane = threadIdx.x & 63;
    f32x4 v[4];
    #pragma unroll
    for (int i = 0; i < 4; ++i) {
        const int col = i * 256 + lane * 4;
        const size_t o = (size_t)row * 1024 + col;
        f32x4 a0 = *reinterpret_cast<const f32x4*>(&p0[o]);
        f32x4 a1 = *reinterpret_cast<const f32x4*>(&p1[o]);
        f32x4 bs = *reinterpret_cast<const f32x4*>(&bias[col]);
        f32x4 rs = *reinterpret_cast<const f32x4*>(&resid[o]);
        v[i] = a0 + a1 + bs + rs;
    }
    ln_body(v, row, lane, g, b, xf, xb);
}

__global__ __launch_bounds__(256) void cvt_bf16(
    const float* __restrict__ in, unsigned short* __restrict__ out, int n)
{
    const int i = (blockIdx.x * 256 + threadIdx.x) * 4;
    if (i >= n) return;
    f32x4 v = *reinterpret_cast<const f32x4*>(&in[i]);
    u16x4 pk;
    #pragma unroll
    for (int j = 0; j < 4; ++j) pk[j] = f2bf(v[j]);
    *reinterpret_cast<u16x4*>(&out[i]) = pk;
}

// ---------------------------------------------------------------------------
// Per-layer weight pack (fp32->bf16, Q-scale folded):
//   [0,3DD) sa qkv  [3DD,6DD) ca qkv  [6DD,7DD) sa_wo  [7DD,8DD) ca_wo
//   [8DD,12DD) w1   [12DD,16DD) w2
// ---------------------------------------------------------------------------
__global__ __launch_bounds__(256) void pack_layer_w(
    const float* __restrict__ sa_wq, const float* __restrict__ sa_wk, const float* __restrict__ sa_wv,
    const float* __restrict__ ca_wq, const float* __restrict__ ca_wk, const float* __restrict__ ca_wv,
    const float* __restrict__ sa_wo, const float* __restrict__ ca_wo,
    const float* __restrict__ w1,   const float* __restrict__ w2,
    unsigned short* __restrict__ dst, int layer)
{
    const size_t DD = 1024u * 1024u;
    const size_t e  = ((size_t)blockIdx.x * 256 + threadIdx.x) * 4;
    const float* src;
    float scale = 1.f;
    if (e < 3 * DD) {
        const int part = (int)(e / DD);
        src = (part == 0 ? sa_wq : part == 1 ? sa_wk : sa_wv) + layer * DD + (e % DD);
        if (part == 0) scale = 0.125f;
    } else if (e < 6 * DD) {
        const size_t r = e - 3 * DD;
        const int part = (int)(r / DD);
        src = (part == 0 ? ca_wq : part == 1 ? ca_wk : ca_wv) + layer * DD + (r % DD);
        if (part == 0) scale = 0.125f;
    } else if (e < 7 * DD)  { src = sa_wo + layer * DD + (e - 6 * DD); }
    else if (e < 8 * DD)    { src = ca_wo + layer * DD + (e - 7 * DD); }
    else if (e < 12 * DD)   { src = w1 + (size_t)layer * 4 * DD + (e - 8 * DD); }
    else                    { src = w2 + (size_t)layer * 4 * DD + (e - 12 * DD); }
    f32x4 v = *reinterpret_cast<const f32x4*>(src);
    u16x4 pk;
    #pragma unroll
    for (int j = 0; j < 4; ++j) pk[j] = f2bf(v[j] * scale);
    *reinterpret_cast<u16x4*>(&dst[e]) = pk;
}

__global__ __launch_bounds__(256) void pack_bias(
    const float* __restrict__ sa_bq, const float* __restrict__ sa_bk, const float* __restrict__ sa_bv,
    const float* __restrict__ ca_bq, const float* __restrict__ ca_bk, const float* __restrict__ ca_bv,
    float* __restrict__ sab, float* __restrict__ cab)
{
    const int idx = blockIdx.x * 256 + threadIdx.x;
    const int half = idx / 12288;
    const int r    = idx % 12288;
    const int l    = r / 3072;
    const int pc   = r % 3072;
    const int part = pc >> 10;
    const int c    = pc & 1023;
    const float* src = half == 0 ? (part == 0 ? sa_bq : part == 1 ? sa_bk : sa_bv)
                                 : (part == 0 ? ca_bq : part == 1 ? ca_bk : ca_bv);
    const float v = src[l * 1024 + c] * (part == 0 ? 0.125f : 1.f);
    (half ? cab : sab)[l * 3072 + pc] = v;
}

// ---------------------------------------------------------------------------
extern "C" void kernel_launch(void* const* d_in, const int* in_sizes, int n_in,
                              void* d_out, int out_size, void* d_ws, size_t ws_size,
                              hipStream_t stream)
{
    (void)in_sizes; (void)n_in; (void)out_size; (void)ws_size;
    const int M  = 4096;
    const int Dm = 1024;
    const size_t DD = (size_t)Dm * Dm;

    const float* tgt   = (const float*)d_in[0];
    const float* mem   = (const float*)d_in[1];
    const float* sa_wq = (const float*)d_in[2];
    const float* sa_wk = (const float*)d_in[3];
    const float* sa_wv = (const float*)d_in[4];
    const float* sa_wo = (const float*)d_in[5];
    const float* sa_bq = (const float*)d_in[6];
    const float* sa_bk = (const float*)d_in[7];
    const float* sa_bv = (const float*)d_in[8];
    const float* sa_bo = (const float*)d_in[9];
    const float* ca_wq = (const float*)d_in[10];
    const float* ca_wk = (const float*)d_in[11];
    const float* ca_wv = (const float*)d_in[12];
    const float* ca_wo = (const float*)d_in[13];
    const float* ca_bq = (const float*)d_in[14];
    const float* ca_bk = (const float*)d_in[15];
    const float* ca_bv = (const float*)d_in[16];
    const float* ca_bo = (const float*)d_in[17];
    const float* w1    = (const float*)d_in[18];
    const float* b1    = (const float*)d_in[19];
    const float* w2    = (const float*)d_in[20];
    const float* b2    = (const float*)d_in[21];
    const float* ln1g  = (const float*)d_in[22];
    const float* ln1b  = (const float*)d_in[23];
    const float* ln2g  = (const float*)d_in[24];
    const float* ln2b  = (const float*)d_in[25];
    const float* ln3g  = (const float*)d_in[26];
    const float* ln3b  = (const float*)d_in[27];
    const float* lnfg  = (const float*)d_in[28];
    const float* lnfb  = (const float*)d_in[29];

    char* p = (char*)d_ws;
    float*          x_f    = (float*)p;          p += (size_t)M * Dm * 4;
    unsigned short* x_b    = (unsigned short*)p; p += (size_t)M * Dm * 2;
    unsigned short* mem_b  = (unsigned short*)p; p += (size_t)M * Dm * 2;
    unsigned short* qkv_b  = (unsigned short*)p; p += (size_t)M * 3072 * 2;
    unsigned short* cakv_b = (unsigned short*)p; p += (size_t)M * 2048 * 2;
    unsigned short* caq_b  = (unsigned short*)p; p += (size_t)M * Dm * 2;
    unsigned short* ao_b   = (unsigned short*)p; p += (size_t)M * Dm * 2;
    unsigned short* wpack  = (unsigned short*)p; p += 16 * DD * 2;
    float*          sab    = (float*)p;          p += 4 * 3072 * 4;
    float*          cab    = (float*)p;          p += 4 * 3072 * 4;
    unsigned short* h_b    = qkv_b;                                          // [4096][4096] bf16
    float*          parA   = (float*)qkv_b;                                  // dead Q/K/V
    float*          parB   = (float*)cakv_b;                                 // dead ca K/V
    float*          par0   = (float*)((char*)qkv_b + (size_t)M * 4096 * 2);  // cakv tail + caq
    float*          par1   = (float*)wpack;                                  // dead packed weights

    dim3 blk(256), blkA(128);

    cvt_bf16<<<4096, blk, 0, stream>>>(tgt, x_b, M * Dm);
    cvt_bf16<<<4096, blk, 0, stream>>>(mem, mem_b, M * Dm);
    pack_bias<<<96, blk, 0, stream>>>(sa_bq, sa_bk, sa_bv, ca_bq, ca_bk, ca_bv, sab, cab);

    const float* res = tgt;
    for (int i = 0; i < 4; ++i) {
        pack_layer_w<<<16384, blk, 0, stream>>>(sa_wq, sa_wk, sa_wv, ca_wq, ca_wk, ca_wv,
                                                sa_wo, ca_wo, w1, w2, wpack, i);
        // --- self-attention ---
        gemm128<<<dim3(24, 32, 1), blk, 0, stream>>>(x_b, wpack, sab + i * 3072,
            qkv_b, nullptr, nullptr, 3072, 1024, 1024, 0);
        attn_fused<<<512, blkA, 0, stream>>>(qkv_b, 3072, qkv_b + 1024, 3072, qkv_b + 2048, 3072, ao_b, 1);
        gemm128<<<dim3(8, 32, 2), blk, 0, stream>>>(ao_b, wpack + 6 * DD, nullptr,
            nullptr, parA, parB, 1024, 1024, 512, 3);
        ln_red2<<<1024, blk, 0, stream>>>(parA, parB, sa_bo + i * Dm, res,
            ln1g + i * Dm, ln1b + i * Dm, x_f, x_b);
        res = x_f;
        // --- cross-attention (caQ + caKV in ONE dispatch) ---
        gemm128_ca<<<dim3(24, 32, 1), blk, 0, stream>>>(x_b, mem_b,
            wpack + 3 * DD, wpack + 4 * DD,
            cab + i * 3072, cab + i * 3072 + 1024,
            caq_b, cakv_b, 1024, 1024);
        attn_fused<<<512, blkA, 0, stream>>>(caq_b, 1024, cakv_b, 2048, cakv_b + 1024, 2048, ao_b, 0);
        gemm128<<<dim3(8, 32, 2), blk, 0, stream>>>(ao_b, wpack + 7 * DD, nullptr,
            nullptr, parA, parB, 1024, 1024, 512, 3);
        ln_red2<<<1024, blk, 0, stream>>>(parA, parB, ca_bo + i * Dm, x_f,
            ln2g + i * Dm, ln2b + i * Dm, x_f, x_b);
        // --- FFN ---
        gemm128<<<dim3(32, 32, 1), blk, 0, stream>>>(x_b, wpack + 8 * DD, b1 + i * 4096,
            h_b, nullptr, nullptr, 4096, 1024, 1024, 1);
        gemm128<<<dim3(8, 32, 2), blk, 0, stream>>>(h_b, wpack + 12 * DD, nullptr,
            nullptr, par0, par1, 1024, 4096, 2048, 3);
        ln_red2<<<1024, blk, 0, stream>>>(par0, par1, b2 + i * Dm, x_f,
            ln3g + i * Dm, ln3b + i * Dm, x_f, x_b);
    }
    ln_kernel<<<1024, blk, 0, stream>>>(x_f, lnfg, lnfb, (float*)d_out, nullptr);
}

// Round 11
// 1275.307 us; speedup vs baseline: 1.6299x; 1.6299x over previous
//
#include <hip/hip_runtime.h>

// ---------------------------------------------------------------------------
// 4-layer transformer decoder, bf16 MFMA implementation (round 11).
// = round 8 (best, 1323 us) with: (a) split-K partials in BF16 (halves the
// partial write+read traffic through ln_red2), (b) fused input cvt launch.
// gemm128: 128x128, BK=32, 2-buf issue-early, 4 blocks/CU, slot-XOR swizzle,
// XCD band swizzle. Out-proj: split-K2 + ln_red2. caQ+caKV dual-job.
// attn: 128-thr blocks + causal tile-skip.
// ---------------------------------------------------------------------------

typedef __attribute__((ext_vector_type(4))) float f32x4;
typedef __attribute__((ext_vector_type(8))) short bf16x8;
typedef __attribute__((ext_vector_type(4))) unsigned short u16x4;
typedef __attribute__((ext_vector_type(4))) unsigned int   u32x4;

__device__ __forceinline__ unsigned short f2bf(float f) {
    unsigned int u = __builtin_bit_cast(unsigned int, f);
    u += 0x7fffu + ((u >> 16) & 1u);   // RNE
    return (unsigned short)(u >> 16);
}
__device__ __forceinline__ float bf2f(unsigned short u) {
    return __builtin_bit_cast(float, (unsigned int)u << 16);
}

__device__ __forceinline__ void gll16(const unsigned short* g, unsigned short* l) {
    auto* gp = reinterpret_cast<const __attribute__((address_space(1))) unsigned int*>(
        reinterpret_cast<uintptr_t>(g));
    auto* lp = reinterpret_cast<__attribute__((address_space(3))) unsigned int*>(
        reinterpret_cast<uintptr_t>(l));
    __builtin_amdgcn_global_load_lds(gp, lp, 16, 0, 0);
}

// ---------------------------------------------------------------------------
// Shared 128x128 GEMM body (r8-proven): both operands staged via gll16 into
// 2-buffer LDS, issue-early prefetch, one syncthreads per K-step.
// mode 0: bf16(acc+bias)  1: bf16(relu(acc+bias))  3: bf16 raw partial -> po
// ---------------------------------------------------------------------------
__device__ __forceinline__ void gemm_body(
    const unsigned short* __restrict__ A,
    const unsigned short* __restrict__ Bw,
    const float* __restrict__ bias,
    unsigned short* __restrict__ outb,
    unsigned short* __restrict__ po,
    int N, int lda, int klen, int mode,
    int m0, int n0, int kz,
    unsigned short (*Al)[128 * 32], unsigned short (*Bl)[128 * 32])
{
    const int tid  = threadIdx.x;
    const int lane = tid & 63;
    const int w    = tid >> 6;
    const int wr   = (w >> 1) * 64;
    const int wc   = (w & 1) * 64;
    const int l15  = lane & 15;
    const int l4   = lane >> 4;

    const int srow = w * 16 + (lane >> 2);
    const int scol = ((lane & 3) ^ ((srow >> 1) & 3)) * 8;
    const unsigned short* ag = A  + (size_t)(m0 + srow) * lda + kz + scol;
    const unsigned short* bg = Bw + (size_t)(n0 + srow) * lda + kz + scol;
    const size_t jstep = (size_t)64 * lda;
    const int lbase = (w * 16) * 32;

    int aoff[4], boff[4];
    #pragma unroll
    for (int i = 0; i < 4; ++i) {
        const int ra = wr + i * 16 + l15;
        const int rb = wc + i * 16 + l15;
        aoff[i] = ra * 32 + ((l4 ^ ((ra >> 1) & 3)) * 8);
        boff[i] = rb * 32 + ((l4 ^ ((rb >> 1) & 3)) * 8);
    }

    f32x4 acc[4][4];
    #pragma unroll
    for (int mi = 0; mi < 4; ++mi)
        #pragma unroll
        for (int ni = 0; ni < 4; ++ni)
            acc[mi][ni] = (f32x4){0.f, 0.f, 0.f, 0.f};

    #pragma unroll
    for (int j = 0; j < 2; ++j) {
        gll16(ag + j * jstep, &Al[0][lbase + j * 64 * 32]);
        gll16(bg + j * jstep, &Bl[0][lbase + j * 64 * 32]);
    }
    __syncthreads();

    const int nt = klen >> 5;
    int cur = 0;
    for (int t = 0; t < nt; ++t) {
        if (t + 1 < nt) {
            ag += 32; bg += 32;
            #pragma unroll
            for (int j = 0; j < 2; ++j) {
                gll16(ag + j * jstep, &Al[cur ^ 1][lbase + j * 64 * 32]);
                gll16(bg + j * jstep, &Bl[cur ^ 1][lbase + j * 64 * 32]);
            }
        }
        const unsigned short* ac = &Al[cur][0];
        const unsigned short* bc = &Bl[cur][0];
        bf16x8 af[4], bf[4];
        #pragma unroll
        for (int i = 0; i < 4; ++i) af[i] = *reinterpret_cast<const bf16x8*>(&ac[aoff[i]]);
        #pragma unroll
        for (int i = 0; i < 4; ++i) bf[i] = *reinterpret_cast<const bf16x8*>(&bc[boff[i]]);
        #pragma unroll
        for (int mi = 0; mi < 4; ++mi)
            #pragma unroll
            for (int ni = 0; ni < 4; ++ni)
                acc[mi][ni] = __builtin_amdgcn_mfma_f32_16x16x32_bf16(af[mi], bf[ni], acc[mi][ni], 0, 0, 0);
        __syncthreads();
        cur ^= 1;
    }

    // epilogue: C/D layout col = lane&15, row = (lane>>4)*4 + r
    #pragma unroll
    for (int mi = 0; mi < 4; ++mi) {
        #pragma unroll
        for (int ni = 0; ni < 4; ++ni) {
            const int col = n0 + wc + ni * 16 + l15;
            const float bs = (mode == 3) ? 0.f : bias[col];
            #pragma unroll
            for (int r = 0; r < 4; ++r) {
                const int row = m0 + wr + mi * 16 + l4 * 4 + r;
                const float val = acc[mi][ni][r] + bs;
                if (mode == 0)      outb[(size_t)row * N + col] = f2bf(val);
                else if (mode == 1) outb[(size_t)row * N + col] = f2bf(fmaxf(val, 0.f));
                else                po[(size_t)row * N + col] = f2bf(val);
            }
        }
    }
}

// gemm128: XCD band swizzle (gy == 32, nwg % 8 == 0); split-K via blockIdx.z
// writes bf16 partials to pb0/pb1.
__global__ __launch_bounds__(256, 4) void gemm128(
    const unsigned short* __restrict__ A,
    const unsigned short* __restrict__ Bw,
    const float* __restrict__ bias,
    unsigned short* __restrict__ outb,
    unsigned short* __restrict__ pb0,
    unsigned short* __restrict__ pb1,
    int N, int lda, int klen, int mode)
{
    __shared__ unsigned short Al[2][128 * 32];
    __shared__ unsigned short Bl[2][128 * 32];
    const int gx   = gridDim.x;
    const int orig = blockIdx.y * gx + blockIdx.x;
    const int xcd  = orig & 7;
    const int lin  = orig >> 3;
    const int m0   = (xcd * 4 + (lin & 3)) * 128;
    const int n0   = (lin >> 2) * 128;
    const int kz   = blockIdx.z * klen;
    unsigned short* po = (blockIdx.z == 0) ? pb0 : pb1;
    gemm_body(A, Bw, bias, outb, po, N, lda, klen, mode, m0, n0, kz, Al, Bl);
}

// gemm128_ca: dual-job dispatch (caQ N=1024 | caKV N=2048), both mode 0.
__global__ __launch_bounds__(256, 4) void gemm128_ca(
    const unsigned short* __restrict__ A0, const unsigned short* __restrict__ A1,
    const unsigned short* __restrict__ B0, const unsigned short* __restrict__ B1,
    const float* __restrict__ bias0, const float* __restrict__ bias1,
    unsigned short* __restrict__ out0, unsigned short* __restrict__ out1,
    int lda, int klen)
{
    __shared__ unsigned short Al[2][128 * 32];
    __shared__ unsigned short Bl[2][128 * 32];
    const int grp = (blockIdx.x >= 8);
    const int bx  = blockIdx.x - (grp ? 8 : 0);
    const int lgx = grp ? 16 : 8;
    const int orig = blockIdx.y * lgx + bx;
    const int xcd  = orig & 7;
    const int lin  = orig >> 3;
    const int m0   = (xcd * 4 + (lin & 3)) * 128;
    const int n0   = (lin >> 2) * 128;
    gemm_body(grp ? A1 : A0, grp ? B1 : B0, grp ? bias1 : bias0,
              grp ? out1 : out0, nullptr, grp ? 2048 : 1024, lda, klen, 0,
              m0, n0, 0, Al, Bl);
}

// ---------------------------------------------------------------------------
// Fused attention: 128-thread blocks (2 waves), grid 512 = (n,h,thalf).
// Causal: wave-uniform tile-skip in QK and PV.
// ---------------------------------------------------------------------------
__global__ __launch_bounds__(128) void attn_fused(
    const unsigned short* __restrict__ Q, int qs,
    const unsigned short* __restrict__ Kb, int ks_,
    const unsigned short* __restrict__ Vb, int vs,
    unsigned short* __restrict__ O,
    int causal)
{
    __shared__ unsigned short Kl[8][256][8];        // 32 KB
    __shared__ unsigned short Vt[32][64][8];        // 32 KB
    __shared__ unsigned short Pl[2][32][16][8];     // 16 KB
    const int tid   = threadIdx.x;
    const int lane  = tid & 63;
    const int w     = tid >> 6;
    const int bxi   = blockIdx.x;
    const int n     = bxi >> 5;
    const int h     = (bxi >> 1) & 15;
    const int thalf = bxi & 1;
    const int l15   = lane & 15;
    const int l4    = lane >> 4;
    const size_t hoff = (size_t)h * 64;

    #pragma unroll
    for (int i = 0; i < 16; ++i) {
        const int e = i * 128 + tid;
        const int s = e >> 3;
        const int c = e & 7;
        u32x4 kv = *reinterpret_cast<const u32x4*>(&Kb[((size_t)s * 16 + n) * ks_ + hoff + c * 8]);
        *reinterpret_cast<u32x4*>(&Kl[c][s][0]) = kv;
        u32x4 vv = *reinterpret_cast<const u32x4*>(&Vb[((size_t)s * 16 + n) * vs + hoff + c * 8]);
        const unsigned short* ve = reinterpret_cast<const unsigned short*>(&vv);
        #pragma unroll
        for (int j = 0; j < 8; ++j)
            Vt[s >> 3][c * 8 + j][s & 7] = ve[j];
    }
    __syncthreads();

    for (int ch = 0; ch < 4; ++ch) {
        const int t0 = thalf * 128 + w * 64 + ch * 16;
        bf16x8 qa[2];
        #pragma unroll
        for (int ks = 0; ks < 2; ++ks)
            qa[ks] = *reinterpret_cast<const bf16x8*>(
                &Q[((size_t)(t0 + l15) * 16 + n) * qs + hoff + ks * 32 + l4 * 8]);

        f32x4 sc[16];
        #pragma unroll
        for (int st = 0; st < 16; ++st) {
            if (causal && st * 16 > t0 + 15) {
                sc[st] = (f32x4){-1e9f, -1e9f, -1e9f, -1e9f};
                continue;
            }
            f32x4 a = (f32x4){0.f, 0.f, 0.f, 0.f};
            #pragma unroll
            for (int ks = 0; ks < 2; ++ks) {
                bf16x8 kf = *reinterpret_cast<const bf16x8*>(&Kl[ks * 4 + l4][st * 16 + l15][0]);
                a = __builtin_amdgcn_mfma_f32_16x16x32_bf16(qa[ks], kf, a, 0, 0, 0);
            }
            sc[st] = a;
        }
        if (causal) {
            #pragma unroll
            for (int st = 0; st < 16; ++st) {
                const int sg = st * 16 + l15;
                #pragma unroll
                for (int r = 0; r < 4; ++r) {
                    const int tg = t0 + l4 * 4 + r;
                    if (sg > tg) sc[st][r] = -1e9f;
                }
            }
        }
        #pragma unroll
        for (int r = 0; r < 4; ++r) {
            float mx = -3.0e38f;
            #pragma unroll
            for (int st = 0; st < 16; ++st) mx = fmaxf(mx, sc[st][r]);
            #pragma unroll
            for (int dd = 1; dd < 16; dd <<= 1) mx = fmaxf(mx, __shfl_xor(mx, dd, 64));
            float sum = 0.f;
            #pragma unroll
            for (int st = 0; st < 16; ++st) {
                const float e = __expf(sc[st][r] - mx);
                sc[st][r] = e;
                sum += e;
            }
            #pragma unroll
            for (int dd = 1; dd < 16; dd <<= 1) sum += __shfl_xor(sum, dd, 64);
            const float inv = 1.f / sum;
            const int rl = l4 * 4 + r;
            #pragma unroll
            for (int st = 0; st < 16; ++st) {
                const int sg = st * 16 + l15;
                Pl[w][sg >> 3][rl][sg & 7] = f2bf(sc[st][r] * inv);
            }
        }
        f32x4 oacc[4];
        #pragma unroll
        for (int dt = 0; dt < 4; ++dt) oacc[dt] = (f32x4){0.f, 0.f, 0.f, 0.f};
        #pragma unroll
        for (int kt = 0; kt < 8; ++kt) {
            if (causal && kt * 32 > t0 + 15) continue;
            bf16x8 pa = *reinterpret_cast<const bf16x8*>(&Pl[w][kt * 4 + l4][l15][0]);
            #pragma unroll
            for (int dt = 0; dt < 4; ++dt) {
                bf16x8 vf = *reinterpret_cast<const bf16x8*>(&Vt[kt * 4 + l4][dt * 16 + l15][0]);
                oacc[dt] = __builtin_amdgcn_mfma_f32_16x16x32_bf16(pa, vf, oacc[dt], 0, 0, 0);
            }
        }
        #pragma unroll
        for (int dt = 0; dt < 4; ++dt)
            #pragma unroll
            for (int r = 0; r < 4; ++r)
                O[((size_t)(t0 + l4 * 4 + r) * 16 + n) * 1024 + hoff + dt * 16 + l15] = f2bf(oacc[dt][r]);
    }
}

// ---------------------------------------------------------------------------
// LayerNorm over D=1024, one wave per row (plain and fused-reduce variants)
// ---------------------------------------------------------------------------
__device__ __forceinline__ void ln_body(
    f32x4 (&v)[4], int row, int lane,
    const float* __restrict__ g, const float* __restrict__ b,
    float* __restrict__ xf, unsigned short* __restrict__ xb)
{
    float s = 0.f;
    #pragma unroll
    for (int i = 0; i < 4; ++i) s += v[i][0] + v[i][1] + v[i][2] + v[i][3];
    #pragma unroll
    for (int dd = 1; dd < 64; dd <<= 1) s += __shfl_xor(s, dd, 64);
    const float mu = s * (1.f / 1024.f);
    float q = 0.f;
    #pragma unroll
    for (int i = 0; i < 4; ++i)
        #pragma unroll
        for (int j = 0; j < 4; ++j) { const float d0 = v[i][j] - mu; q += d0 * d0; }
    #pragma unroll
    for (int dd = 1; dd < 64; dd <<= 1) q += __shfl_xor(q, dd, 64);
    const float rstd = rsqrtf(q * (1.f / 1024.f) + 1e-5f);
    #pragma unroll
    for (int i = 0; i < 4; ++i) {
        const int col = i * 256 + lane * 4;
        f32x4 gg = *reinterpret_cast<const f32x4*>(&g[col]);
        f32x4 bb = *reinterpret_cast<const f32x4*>(&b[col]);
        f32x4 y;
        #pragma unroll
        for (int j = 0; j < 4; ++j) y[j] = (v[i][j] - mu) * rstd * gg[j] + bb[j];
        if (xf) *reinterpret_cast<f32x4*>(&xf[(size_t)row * 1024 + col]) = y;
        if (xb) {
            u16x4 pk;
            #pragma unroll
            for (int j = 0; j < 4; ++j) pk[j] = f2bf(y[j]);
            *reinterpret_cast<u16x4*>(&xb[(size_t)row * 1024 + col]) = pk;
        }
    }
}

__global__ __launch_bounds__(256) void ln_kernel(
    const float* __restrict__ z, const float* __restrict__ g, const float* __restrict__ b,
    float* __restrict__ xf, unsigned short* __restrict__ xb)
{
    const int row  = blockIdx.x * 4 + (threadIdx.x >> 6);
    const int lane = threadIdx.x & 63;
    f32x4 v[4];
    #pragma unroll
    for (int i = 0; i < 4; ++i)
        v[i] = *reinterpret_cast<const f32x4*>(&z[(size_t)row * 1024 + i * 256 + lane * 4]);
    ln_body(v, row, lane, g, b, xf, xb);
}

// z = bf16(p0) + bf16(p1) + bias + resid, then LN. resid may alias xf.
__global__ __launch_bounds__(256) void ln_red2(
    const unsigned short* __restrict__ p0, const unsigned short* __restrict__ p1,
    const float* __restrict__ bias, const float* __restrict__ resid,
    const float* __restrict__ g, const float* __restrict__ b,
    float* __restrict__ xf, unsigned short* __restrict__ xb)
{
    const int row  = blockIdx.x * 4 + (threadIdx.x >> 6);
    const int lane = threadIdx.x & 63;
    f32x4 v[4];
    #pragma unroll
    for (int i = 0; i < 4; ++i) {
        const int col = i * 256 + lane * 4;
        const size_t o = (size_t)row * 1024 + col;
        u16x4 a0 = *reinterpret_cast<const u16x4*>(&p0[o]);
        u16x4 a1 = *reinterpret_cast<const u16x4*>(&p1[o]);
        f32x4 bs = *reinterpret_cast<const f32x4*>(&bias[col]);
        f32x4 rs = *reinterpret_cast<const f32x4*>(&resid[o]);
        #pragma unroll
        for (int j = 0; j < 4; ++j)
            v[i][j] = bf2f(a0[j]) + bf2f(a1[j]) + bs[j] + rs[j];
    }
    ln_body(v, row, lane, g, b, xf, xb);
}

// fused input conversion: [0,n0) from in0, [n0,n0+n1) from in1
__global__ __launch_bounds__(256) void cvt2_bf16(
    const float* __restrict__ in0, const float* __restrict__ in1,
    unsigned short* __restrict__ out0, unsigned short* __restrict__ out1, int n0)
{
    const int i = (blockIdx.x * 256 + threadIdx.x) * 4;
    const float* src = (i < n0) ? in0 : in1;
    unsigned short* dst = (i < n0) ? out0 : out1;
    const int off = (i < n0) ? i : i - n0;
    f32x4 v = *reinterpret_cast<const f32x4*>(&src[off]);
    u16x4 pk;
    #pragma unroll
    for (int j = 0; j < 4; ++j) pk[j] = f2bf(v[j]);
    *reinterpret_cast<u16x4*>(&dst[off]) = pk;
}

// ---------------------------------------------------------------------------
// Per-layer weight pack (fp32->bf16, Q-scale folded):
//   [0,3DD) sa qkv  [3DD,6DD) ca qkv  [6DD,7DD) sa_wo  [7DD,8DD) ca_wo
//   [8DD,12DD) w1   [12DD,16DD) w2
// ---------------------------------------------------------------------------
__global__ __launch_bounds__(256) void pack_layer_w(
    const float* __restrict__ sa_wq, const float* __restrict__ sa_wk, const float* __restrict__ sa_wv,
    const float* __restrict__ ca_wq, const float* __restrict__ ca_wk, const float* __restrict__ ca_wv,
    const float* __restrict__ sa_wo, const float* __restrict__ ca_wo,
    const float* __restrict__ w1,   const float* __restrict__ w2,
    unsigned short* __restrict__ dst, int layer)
{
    const size_t DD = 1024u * 1024u;
    const size_t e  = ((size_t)blockIdx.x * 256 + threadIdx.x) * 4;
    const float* src;
    float scale = 1.f;
    if (e < 3 * DD) {
        const int part = (int)(e / DD);
        src = (part == 0 ? sa_wq : part == 1 ? sa_wk : sa_wv) + layer * DD + (e % DD);
        if (part == 0) scale = 0.125f;
    } else if (e < 6 * DD) {
        const size_t r = e - 3 * DD;
        const int part = (int)(r / DD);
        src = (part == 0 ? ca_wq : part == 1 ? ca_wk : ca_wv) + layer * DD + (r % DD);
        if (part == 0) scale = 0.125f;
    } else if (e < 7 * DD)  { src = sa_wo + layer * DD + (e - 6 * DD); }
    else if (e < 8 * DD)    { src = ca_wo + layer * DD + (e - 7 * DD); }
    else if (e < 12 * DD)   { src = w1 + (size_t)layer * 4 * DD + (e - 8 * DD); }
    else                    { src = w2 + (size_t)layer * 4 * DD + (e - 12 * DD); }
    f32x4 v = *reinterpret_cast<const f32x4*>(src);
    u16x4 pk;
    #pragma unroll
    for (int j = 0; j < 4; ++j) pk[j] = f2bf(v[j] * scale);
    *reinterpret_cast<u16x4*>(&dst[e]) = pk;
}

__global__ __launch_bounds__(256) void pack_bias(
    const float* __restrict__ sa_bq, const float* __restrict__ sa_bk, const float* __restrict__ sa_bv,
    const float* __restrict__ ca_bq, const float* __restrict__ ca_bk, const float* __restrict__ ca_bv,
    float* __restrict__ sab, float* __restrict__ cab)
{
    const int idx = blockIdx.x * 256 + threadIdx.x;
    const int half = idx / 12288;
    const int r    = idx % 12288;
    const int l    = r / 3072;
    const int pc   = r % 3072;
    const int part = pc >> 10;
    const int c    = pc & 1023;
    const float* src = half == 0 ? (part == 0 ? sa_bq : part == 1 ? sa_bk : sa_bv)
                                 : (part == 0 ? ca_bq : part == 1 ? ca_bk : ca_bv);
    const float v = src[l * 1024 + c] * (part == 0 ? 0.125f : 1.f);
    (half ? cab : sab)[l * 3072 + pc] = v;
}

// ---------------------------------------------------------------------------
extern "C" void kernel_launch(void* const* d_in, const int* in_sizes, int n_in,
                              void* d_out, int out_size, void* d_ws, size_t ws_size,
                              hipStream_t stream)
{
    (void)in_sizes; (void)n_in; (void)out_size; (void)ws_size;
    const int M  = 4096;
    const int Dm = 1024;
    const size_t DD = (size_t)Dm * Dm;

    const float* tgt   = (const float*)d_in[0];
    const float* mem   = (const float*)d_in[1];
    const float* sa_wq = (const float*)d_in[2];
    const float* sa_wk = (const float*)d_in[3];
    const float* sa_wv = (const float*)d_in[4];
    const float* sa_wo = (const float*)d_in[5];
    const float* sa_bq = (const float*)d_in[6];
    const float* sa_bk = (const float*)d_in[7];
    const float* sa_bv = (const float*)d_in[8];
    const float* sa_bo = (const float*)d_in[9];
    const float* ca_wq = (const float*)d_in[10];
    const float* ca_wk = (const float*)d_in[11];
    const float* ca_wv = (const float*)d_in[12];
    const float* ca_wo = (const float*)d_in[13];
    const float* ca_bq = (const float*)d_in[14];
    const float* ca_bk = (const float*)d_in[15];
    const float* ca_bv = (const float*)d_in[16];
    const float* ca_bo = (const float*)d_in[17];
    const float* w1    = (const float*)d_in[18];
    const float* b1    = (const float*)d_in[19];
    const float* w2    = (const float*)d_in[20];
    const float* b2    = (const float*)d_in[21];
    const float* ln1g  = (const float*)d_in[22];
    const float* ln1b  = (const float*)d_in[23];
    const float* ln2g  = (const float*)d_in[24];
    const float* ln2b  = (const float*)d_in[25];
    const float* ln3g  = (const float*)d_in[26];
    const float* ln3b  = (const float*)d_in[27];
    const float* lnfg  = (const float*)d_in[28];
    const float* lnfb  = (const float*)d_in[29];

    char* p = (char*)d_ws;
    float*          x_f    = (float*)p;          p += (size_t)M * Dm * 4;       // 16.78 MB
    unsigned short* x_b    = (unsigned short*)p; p += (size_t)M * Dm * 2;
    unsigned short* mem_b  = (unsigned short*)p; p += (size_t)M * Dm * 2;
    unsigned short* qkv_b  = (unsigned short*)p; p += (size_t)M * 3072 * 2;     // 25.17 MB
    unsigned short* cakv_b = (unsigned short*)p; p += (size_t)M * 2048 * 2;     // 16.78 MB
    unsigned short* caq_b  = (unsigned short*)p; p += (size_t)M * Dm * 2;
    unsigned short* ao_b   = (unsigned short*)p; p += (size_t)M * Dm * 2;
    unsigned short* wpack  = (unsigned short*)p; p += 16 * DD * 2;              // 33.55 MB
    float*          sab    = (float*)p;          p += 4 * 3072 * 4;
    float*          cab    = (float*)p;          p += 4 * 3072 * 4;
    unsigned short* h_b    = qkv_b;                                             // [4096][4096] bf16
    // bf16 split-K partials (8.39 MB each, live only gemm -> ln_red2):
    unsigned short* parA   = qkv_b;                                             // dead Q/K/V
    unsigned short* parB   = cakv_b;                                            // dead ca K/V
    unsigned short* par0   = (unsigned short*)((char*)qkv_b + (size_t)M * 4096 * 2); // cakv tail+caq
    unsigned short* par1   = wpack;                                             // dead packed sa-qkv

    dim3 blk(256), blkA(128);

    cvt2_bf16<<<8192, blk, 0, stream>>>(tgt, mem, x_b, mem_b, M * Dm);
    pack_bias<<<96, blk, 0, stream>>>(sa_bq, sa_bk, sa_bv, ca_bq, ca_bk, ca_bv, sab, cab);

    const float* res = tgt;
    for (int i = 0; i < 4; ++i) {
        pack_layer_w<<<16384, blk, 0, stream>>>(sa_wq, sa_wk, sa_wv, ca_wq, ca_wk, ca_wv,
                                                sa_wo, ca_wo, w1, w2, wpack, i);
        // --- self-attention ---
        gemm128<<<dim3(24, 32, 1), blk, 0, stream>>>(x_b, wpack, sab + i * 3072,
            qkv_b, nullptr, nullptr, 3072, 1024, 1024, 0);
        attn_fused<<<512, blkA, 0, stream>>>(qkv_b, 3072, qkv_b + 1024, 3072, qkv_b + 2048, 3072, ao_b, 1);
        gemm128<<<dim3(8, 32, 2), blk, 0, stream>>>(ao_b, wpack + 6 * DD, nullptr,
            nullptr, parA, parB, 1024, 1024, 512, 3);
        ln_red2<<<1024, blk, 0, stream>>>(parA, parB, sa_bo + i * Dm, res,
            ln1g + i * Dm, ln1b + i * Dm, x_f, x_b);
        res = x_f;
        // --- cross-attention (caQ + caKV in ONE dispatch) ---
        gemm128_ca<<<dim3(24, 32, 1), blk, 0, stream>>>(x_b, mem_b,
            wpack + 3 * DD, wpack + 4 * DD,
            cab + i * 3072, cab + i * 3072 + 1024,
            caq_b, cakv_b, 1024, 1024);
        attn_fused<<<512, blkA, 0, stream>>>(caq_b, 1024, cakv_b, 2048, cakv_b + 1024, 2048, ao_b, 0);
        gemm128<<<dim3(8, 32, 2), blk, 0, stream>>>(ao_b, wpack + 7 * DD, nullptr,
            nullptr, parA, parB, 1024, 1024, 512, 3);
        ln_red2<<<1024, blk, 0, stream>>>(parA, parB, ca_bo + i * Dm, x_f,
            ln2g + i * Dm, ln2b + i * Dm, x_f, x_b);
        // --- FFN ---
        gemm128<<<dim3(32, 32, 1), blk, 0, stream>>>(x_b, wpack + 8 * DD, b1 + i * 4096,
            h_b, nullptr, nullptr, 4096, 1024, 1024, 1);
        gemm128<<<dim3(8, 32, 2), blk, 0, stream>>>(h_b, wpack + 12 * DD, nullptr,
            nullptr, par0, par1, 1024, 4096, 2048, 3);
        ln_red2<<<1024, blk, 0, stream>>>(par0, par1, b2 + i * Dm, x_f,
            ln3g + i * Dm, ln3b + i * Dm, x_f, x_b);
    }
    ln_kernel<<<1024, blk, 0, stream>>>(x_f, lnfg, lnfb, (float*)d_out, nullptr);
}

// Round 12
// 1243.355 us; speedup vs baseline: 1.6718x; 1.0257x over previous
//
#include <hip/hip_runtime.h>

// ---------------------------------------------------------------------------
// 4-layer transformer decoder, bf16 MFMA implementation (round 12).
// = round 11 (1275 us) + BF16 residual stream: one bf16 buffer x_b serves
// residual + GEMM input; every LN reads/writes bf16 (halves LN traffic).
// gemm128: 128x128, BK=32, 2-buf issue-early, 4 blocks/CU, slot-XOR swizzle,
// XCD band swizzle, bf16 split-K partials. Out-proj: split-K2 + ln_red2.
// caQ+caKV dual-job. attn: 128-thr blocks + causal tile-skip.
// ---------------------------------------------------------------------------

typedef __attribute__((ext_vector_type(4))) float f32x4;
typedef __attribute__((ext_vector_type(8))) short bf16x8;
typedef __attribute__((ext_vector_type(4))) unsigned short u16x4;
typedef __attribute__((ext_vector_type(4))) unsigned int   u32x4;

__device__ __forceinline__ unsigned short f2bf(float f) {
    unsigned int u = __builtin_bit_cast(unsigned int, f);
    u += 0x7fffu + ((u >> 16) & 1u);   // RNE
    return (unsigned short)(u >> 16);
}
__device__ __forceinline__ float bf2f(unsigned short u) {
    return __builtin_bit_cast(float, (unsigned int)u << 16);
}

__device__ __forceinline__ void gll16(const unsigned short* g, unsigned short* l) {
    auto* gp = reinterpret_cast<const __attribute__((address_space(1))) unsigned int*>(
        reinterpret_cast<uintptr_t>(g));
    auto* lp = reinterpret_cast<__attribute__((address_space(3))) unsigned int*>(
        reinterpret_cast<uintptr_t>(l));
    __builtin_amdgcn_global_load_lds(gp, lp, 16, 0, 0);
}

// ---------------------------------------------------------------------------
// Shared 128x128 GEMM body (r8-proven): both operands staged via gll16 into
// 2-buffer LDS, issue-early prefetch, one syncthreads per K-step.
// mode 0: bf16(acc+bias)  1: bf16(relu(acc+bias))  3: bf16 raw partial -> po
// ---------------------------------------------------------------------------
__device__ __forceinline__ void gemm_body(
    const unsigned short* __restrict__ A,
    const unsigned short* __restrict__ Bw,
    const float* __restrict__ bias,
    unsigned short* __restrict__ outb,
    unsigned short* __restrict__ po,
    int N, int lda, int klen, int mode,
    int m0, int n0, int kz,
    unsigned short (*Al)[128 * 32], unsigned short (*Bl)[128 * 32])
{
    const int tid  = threadIdx.x;
    const int lane = tid & 63;
    const int w    = tid >> 6;
    const int wr   = (w >> 1) * 64;
    const int wc   = (w & 1) * 64;
    const int l15  = lane & 15;
    const int l4   = lane >> 4;

    const int srow = w * 16 + (lane >> 2);
    const int scol = ((lane & 3) ^ ((srow >> 1) & 3)) * 8;
    const unsigned short* ag = A  + (size_t)(m0 + srow) * lda + kz + scol;
    const unsigned short* bg = Bw + (size_t)(n0 + srow) * lda + kz + scol;
    const size_t jstep = (size_t)64 * lda;
    const int lbase = (w * 16) * 32;

    int aoff[4], boff[4];
    #pragma unroll
    for (int i = 0; i < 4; ++i) {
        const int ra = wr + i * 16 + l15;
        const int rb = wc + i * 16 + l15;
        aoff[i] = ra * 32 + ((l4 ^ ((ra >> 1) & 3)) * 8);
        boff[i] = rb * 32 + ((l4 ^ ((rb >> 1) & 3)) * 8);
    }

    f32x4 acc[4][4];
    #pragma unroll
    for (int mi = 0; mi < 4; ++mi)
        #pragma unroll
        for (int ni = 0; ni < 4; ++ni)
            acc[mi][ni] = (f32x4){0.f, 0.f, 0.f, 0.f};

    #pragma unroll
    for (int j = 0; j < 2; ++j) {
        gll16(ag + j * jstep, &Al[0][lbase + j * 64 * 32]);
        gll16(bg + j * jstep, &Bl[0][lbase + j * 64 * 32]);
    }
    __syncthreads();

    const int nt = klen >> 5;
    int cur = 0;
    for (int t = 0; t < nt; ++t) {
        if (t + 1 < nt) {
            ag += 32; bg += 32;
            #pragma unroll
            for (int j = 0; j < 2; ++j) {
                gll16(ag + j * jstep, &Al[cur ^ 1][lbase + j * 64 * 32]);
                gll16(bg + j * jstep, &Bl[cur ^ 1][lbase + j * 64 * 32]);
            }
        }
        const unsigned short* ac = &Al[cur][0];
        const unsigned short* bc = &Bl[cur][0];
        bf16x8 af[4], bf[4];
        #pragma unroll
        for (int i = 0; i < 4; ++i) af[i] = *reinterpret_cast<const bf16x8*>(&ac[aoff[i]]);
        #pragma unroll
        for (int i = 0; i < 4; ++i) bf[i] = *reinterpret_cast<const bf16x8*>(&bc[boff[i]]);
        #pragma unroll
        for (int mi = 0; mi < 4; ++mi)
            #pragma unroll
            for (int ni = 0; ni < 4; ++ni)
                acc[mi][ni] = __builtin_amdgcn_mfma_f32_16x16x32_bf16(af[mi], bf[ni], acc[mi][ni], 0, 0, 0);
        __syncthreads();
        cur ^= 1;
    }

    // epilogue: C/D layout col = lane&15, row = (lane>>4)*4 + r
    #pragma unroll
    for (int mi = 0; mi < 4; ++mi) {
        #pragma unroll
        for (int ni = 0; ni < 4; ++ni) {
            const int col = n0 + wc + ni * 16 + l15;
            const float bs = (mode == 3) ? 0.f : bias[col];
            #pragma unroll
            for (int r = 0; r < 4; ++r) {
                const int row = m0 + wr + mi * 16 + l4 * 4 + r;
                const float val = acc[mi][ni][r] + bs;
                if (mode == 0)      outb[(size_t)row * N + col] = f2bf(val);
                else if (mode == 1) outb[(size_t)row * N + col] = f2bf(fmaxf(val, 0.f));
                else                po[(size_t)row * N + col] = f2bf(val);
            }
        }
    }
}

// gemm128: XCD band swizzle (gy == 32, nwg % 8 == 0); split-K via blockIdx.z
// writes bf16 partials to pb0/pb1.
__global__ __launch_bounds__(256, 4) void gemm128(
    const unsigned short* __restrict__ A,
    const unsigned short* __restrict__ Bw,
    const float* __restrict__ bias,
    unsigned short* __restrict__ outb,
    unsigned short* __restrict__ pb0,
    unsigned short* __restrict__ pb1,
    int N, int lda, int klen, int mode)
{
    __shared__ unsigned short Al[2][128 * 32];
    __shared__ unsigned short Bl[2][128 * 32];
    const int gx   = gridDim.x;
    const int orig = blockIdx.y * gx + blockIdx.x;
    const int xcd  = orig & 7;
    const int lin  = orig >> 3;
    const int m0   = (xcd * 4 + (lin & 3)) * 128;
    const int n0   = (lin >> 2) * 128;
    const int kz   = blockIdx.z * klen;
    unsigned short* po = (blockIdx.z == 0) ? pb0 : pb1;
    gemm_body(A, Bw, bias, outb, po, N, lda, klen, mode, m0, n0, kz, Al, Bl);
}

// gemm128_ca: dual-job dispatch (caQ N=1024 | caKV N=2048), both mode 0.
__global__ __launch_bounds__(256, 4) void gemm128_ca(
    const unsigned short* __restrict__ A0, const unsigned short* __restrict__ A1,
    const unsigned short* __restrict__ B0, const unsigned short* __restrict__ B1,
    const float* __restrict__ bias0, const float* __restrict__ bias1,
    unsigned short* __restrict__ out0, unsigned short* __restrict__ out1,
    int lda, int klen)
{
    __shared__ unsigned short Al[2][128 * 32];
    __shared__ unsigned short Bl[2][128 * 32];
    const int grp = (blockIdx.x >= 8);
    const int bx  = blockIdx.x - (grp ? 8 : 0);
    const int lgx = grp ? 16 : 8;
    const int orig = blockIdx.y * lgx + bx;
    const int xcd  = orig & 7;
    const int lin  = orig >> 3;
    const int m0   = (xcd * 4 + (lin & 3)) * 128;
    const int n0   = (lin >> 2) * 128;
    gemm_body(grp ? A1 : A0, grp ? B1 : B0, grp ? bias1 : bias0,
              grp ? out1 : out0, nullptr, grp ? 2048 : 1024, lda, klen, 0,
              m0, n0, 0, Al, Bl);
}

// ---------------------------------------------------------------------------
// Fused attention: 128-thread blocks (2 waves), grid 512 = (n,h,thalf).
// Causal: wave-uniform tile-skip in QK and PV.
// ---------------------------------------------------------------------------
__global__ __launch_bounds__(128) void attn_fused(
    const unsigned short* __restrict__ Q, int qs,
    const unsigned short* __restrict__ Kb, int ks_,
    const unsigned short* __restrict__ Vb, int vs,
    unsigned short* __restrict__ O,
    int causal)
{
    __shared__ unsigned short Kl[8][256][8];        // 32 KB
    __shared__ unsigned short Vt[32][64][8];        // 32 KB
    __shared__ unsigned short Pl[2][32][16][8];     // 16 KB
    const int tid   = threadIdx.x;
    const int lane  = tid & 63;
    const int w     = tid >> 6;
    const int bxi   = blockIdx.x;
    const int n     = bxi >> 5;
    const int h     = (bxi >> 1) & 15;
    const int thalf = bxi & 1;
    const int l15   = lane & 15;
    const int l4    = lane >> 4;
    const size_t hoff = (size_t)h * 64;

    #pragma unroll
    for (int i = 0; i < 16; ++i) {
        const int e = i * 128 + tid;
        const int s = e >> 3;
        const int c = e & 7;
        u32x4 kv = *reinterpret_cast<const u32x4*>(&Kb[((size_t)s * 16 + n) * ks_ + hoff + c * 8]);
        *reinterpret_cast<u32x4*>(&Kl[c][s][0]) = kv;
        u32x4 vv = *reinterpret_cast<const u32x4*>(&Vb[((size_t)s * 16 + n) * vs + hoff + c * 8]);
        const unsigned short* ve = reinterpret_cast<const unsigned short*>(&vv);
        #pragma unroll
        for (int j = 0; j < 8; ++j)
            Vt[s >> 3][c * 8 + j][s & 7] = ve[j];
    }
    __syncthreads();

    for (int ch = 0; ch < 4; ++ch) {
        const int t0 = thalf * 128 + w * 64 + ch * 16;
        bf16x8 qa[2];
        #pragma unroll
        for (int ks = 0; ks < 2; ++ks)
            qa[ks] = *reinterpret_cast<const bf16x8*>(
                &Q[((size_t)(t0 + l15) * 16 + n) * qs + hoff + ks * 32 + l4 * 8]);

        f32x4 sc[16];
        #pragma unroll
        for (int st = 0; st < 16; ++st) {
            if (causal && st * 16 > t0 + 15) {
                sc[st] = (f32x4){-1e9f, -1e9f, -1e9f, -1e9f};
                continue;
            }
            f32x4 a = (f32x4){0.f, 0.f, 0.f, 0.f};
            #pragma unroll
            for (int ks = 0; ks < 2; ++ks) {
                bf16x8 kf = *reinterpret_cast<const bf16x8*>(&Kl[ks * 4 + l4][st * 16 + l15][0]);
                a = __builtin_amdgcn_mfma_f32_16x16x32_bf16(qa[ks], kf, a, 0, 0, 0);
            }
            sc[st] = a;
        }
        if (causal) {
            #pragma unroll
            for (int st = 0; st < 16; ++st) {
                const int sg = st * 16 + l15;
                #pragma unroll
                for (int r = 0; r < 4; ++r) {
                    const int tg = t0 + l4 * 4 + r;
                    if (sg > tg) sc[st][r] = -1e9f;
                }
            }
        }
        #pragma unroll
        for (int r = 0; r < 4; ++r) {
            float mx = -3.0e38f;
            #pragma unroll
            for (int st = 0; st < 16; ++st) mx = fmaxf(mx, sc[st][r]);
            #pragma unroll
            for (int dd = 1; dd < 16; dd <<= 1) mx = fmaxf(mx, __shfl_xor(mx, dd, 64));
            float sum = 0.f;
            #pragma unroll
            for (int st = 0; st < 16; ++st) {
                const float e = __expf(sc[st][r] - mx);
                sc[st][r] = e;
                sum += e;
            }
            #pragma unroll
            for (int dd = 1; dd < 16; dd <<= 1) sum += __shfl_xor(sum, dd, 64);
            const float inv = 1.f / sum;
            const int rl = l4 * 4 + r;
            #pragma unroll
            for (int st = 0; st < 16; ++st) {
                const int sg = st * 16 + l15;
                Pl[w][sg >> 3][rl][sg & 7] = f2bf(sc[st][r] * inv);
            }
        }
        f32x4 oacc[4];
        #pragma unroll
        for (int dt = 0; dt < 4; ++dt) oacc[dt] = (f32x4){0.f, 0.f, 0.f, 0.f};
        #pragma unroll
        for (int kt = 0; kt < 8; ++kt) {
            if (causal && kt * 32 > t0 + 15) continue;
            bf16x8 pa = *reinterpret_cast<const bf16x8*>(&Pl[w][kt * 4 + l4][l15][0]);
            #pragma unroll
            for (int dt = 0; dt < 4; ++dt) {
                bf16x8 vf = *reinterpret_cast<const bf16x8*>(&Vt[kt * 4 + l4][dt * 16 + l15][0]);
                oacc[dt] = __builtin_amdgcn_mfma_f32_16x16x32_bf16(pa, vf, oacc[dt], 0, 0, 0);
            }
        }
        #pragma unroll
        for (int dt = 0; dt < 4; ++dt)
            #pragma unroll
            for (int r = 0; r < 4; ++r)
                O[((size_t)(t0 + l4 * 4 + r) * 16 + n) * 1024 + hoff + dt * 16 + l15] = f2bf(oacc[dt][r]);
    }
}

// ---------------------------------------------------------------------------
// LayerNorm over D=1024, one wave per row. v computed fp32; writes bf16 (xb)
// and/or fp32 (xf).
// ---------------------------------------------------------------------------
__device__ __forceinline__ void ln_body(
    f32x4 (&v)[4], int row, int lane,
    const float* __restrict__ g, const float* __restrict__ b,
    float* __restrict__ xf, unsigned short* __restrict__ xb)
{
    float s = 0.f;
    #pragma unroll
    for (int i = 0; i < 4; ++i) s += v[i][0] + v[i][1] + v[i][2] + v[i][3];
    #pragma unroll
    for (int dd = 1; dd < 64; dd <<= 1) s += __shfl_xor(s, dd, 64);
    const float mu = s * (1.f / 1024.f);
    float q = 0.f;
    #pragma unroll
    for (int i = 0; i < 4; ++i)
        #pragma unroll
        for (int j = 0; j < 4; ++j) { const float d0 = v[i][j] - mu; q += d0 * d0; }
    #pragma unroll
    for (int dd = 1; dd < 64; dd <<= 1) q += __shfl_xor(q, dd, 64);
    const float rstd = rsqrtf(q * (1.f / 1024.f) + 1e-5f);
    #pragma unroll
    for (int i = 0; i < 4; ++i) {
        const int col = i * 256 + lane * 4;
        f32x4 gg = *reinterpret_cast<const f32x4*>(&g[col]);
        f32x4 bb = *reinterpret_cast<const f32x4*>(&b[col]);
        f32x4 y;
        #pragma unroll
        for (int j = 0; j < 4; ++j) y[j] = (v[i][j] - mu) * rstd * gg[j] + bb[j];
        if (xf) *reinterpret_cast<f32x4*>(&xf[(size_t)row * 1024 + col]) = y;
        if (xb) {
            u16x4 pk;
            #pragma unroll
            for (int j = 0; j < 4; ++j) pk[j] = f2bf(y[j]);
            *reinterpret_cast<u16x4*>(&xb[(size_t)row * 1024 + col]) = pk;
        }
    }
}

// z = bf16(p0) + bf16(p1) + bias + bf16(resid); LN -> bf16 xb.
// resid may alias xb (row-local read-then-write).
__global__ __launch_bounds__(256) void ln_red2(
    const unsigned short* __restrict__ p0, const unsigned short* __restrict__ p1,
    const float* __restrict__ bias, const unsigned short* __restrict__ resid,
    const float* __restrict__ g, const float* __restrict__ b,
    unsigned short* __restrict__ xb)
{
    const int row  = blockIdx.x * 4 + (threadIdx.x >> 6);
    const int lane = threadIdx.x & 63;
    f32x4 v[4];
    #pragma unroll
    for (int i = 0; i < 4; ++i) {
        const int col = i * 256 + lane * 4;
        const size_t o = (size_t)row * 1024 + col;
        u16x4 a0 = *reinterpret_cast<const u16x4*>(&p0[o]);
        u16x4 a1 = *reinterpret_cast<const u16x4*>(&p1[o]);
        u16x4 rs = *reinterpret_cast<const u16x4*>(&resid[o]);
        f32x4 bs = *reinterpret_cast<const f32x4*>(&bias[col]);
        #pragma unroll
        for (int j = 0; j < 4; ++j)
            v[i][j] = bf2f(a0[j]) + bf2f(a1[j]) + bs[j] + bf2f(rs[j]);
    }
    ln_body(v, row, lane, g, b, nullptr, xb);
}

// final LN: bf16 input -> fp32 output
__global__ __launch_bounds__(256) void ln_final(
    const unsigned short* __restrict__ z, const float* __restrict__ g,
    const float* __restrict__ b, float* __restrict__ out)
{
    const int row  = blockIdx.x * 4 + (threadIdx.x >> 6);
    const int lane = threadIdx.x & 63;
    f32x4 v[4];
    #pragma unroll
    for (int i = 0; i < 4; ++i) {
        u16x4 zz = *reinterpret_cast<const u16x4*>(&z[(size_t)row * 1024 + i * 256 + lane * 4]);
        #pragma unroll
        for (int j = 0; j < 4; ++j) v[i][j] = bf2f(zz[j]);
    }
    ln_body(v, row, lane, g, b, out, nullptr);
}

// fused input conversion: [0,n0) from in0, rest from in1
__global__ __launch_bounds__(256) void cvt2_bf16(
    const float* __restrict__ in0, const float* __restrict__ in1,
    unsigned short* __restrict__ out0, unsigned short* __restrict__ out1, int n0)
{
    const int i = (blockIdx.x * 256 + threadIdx.x) * 4;
    const float* src = (i < n0) ? in0 : in1;
    unsigned short* dst = (i < n0) ? out0 : out1;
    const int off = (i < n0) ? i : i - n0;
    f32x4 v = *reinterpret_cast<const f32x4*>(&src[off]);
    u16x4 pk;
    #pragma unroll
    for (int j = 0; j < 4; ++j) pk[j] = f2bf(v[j]);
    *reinterpret_cast<u16x4*>(&dst[off]) = pk;
}

// ---------------------------------------------------------------------------
// Per-layer weight pack (fp32->bf16, Q-scale folded):
//   [0,3DD) sa qkv  [3DD,6DD) ca qkv  [6DD,7DD) sa_wo  [7DD,8DD) ca_wo
//   [8DD,12DD) w1   [12DD,16DD) w2
// ---------------------------------------------------------------------------
__global__ __launch_bounds__(256) void pack_layer_w(
    const float* __restrict__ sa_wq, const float* __restrict__ sa_wk, const float* __restrict__ sa_wv,
    const float* __restrict__ ca_wq, const float* __restrict__ ca_wk, const float* __restrict__ ca_wv,
    const float* __restrict__ sa_wo, const float* __restrict__ ca_wo,
    const float* __restrict__ w1,   const float* __restrict__ w2,
    unsigned short* __restrict__ dst, int layer)
{
    const size_t DD = 1024u * 1024u;
    const size_t e  = ((size_t)blockIdx.x * 256 + threadIdx.x) * 4;
    const float* src;
    float scale = 1.f;
    if (e < 3 * DD) {
        const int part = (int)(e / DD);
        src = (part == 0 ? sa_wq : part == 1 ? sa_wk : sa_wv) + layer * DD + (e % DD);
        if (part == 0) scale = 0.125f;
    } else if (e < 6 * DD) {
        const size_t r = e - 3 * DD;
        const int part = (int)(r / DD);
        src = (part == 0 ? ca_wq : part == 1 ? ca_wk : ca_wv) + layer * DD + (r % DD);
        if (part == 0) scale = 0.125f;
    } else if (e < 7 * DD)  { src = sa_wo + layer * DD + (e - 6 * DD); }
    else if (e < 8 * DD)    { src = ca_wo + layer * DD + (e - 7 * DD); }
    else if (e < 12 * DD)   { src = w1 + (size_t)layer * 4 * DD + (e - 8 * DD); }
    else                    { src = w2 + (size_t)layer * 4 * DD + (e - 12 * DD); }
    f32x4 v = *reinterpret_cast<const f32x4*>(src);
    u16x4 pk;
    #pragma unroll
    for (int j = 0; j < 4; ++j) pk[j] = f2bf(v[j] * scale);
    *reinterpret_cast<u16x4*>(&dst[e]) = pk;
}

__global__ __launch_bounds__(256) void pack_bias(
    const float* __restrict__ sa_bq, const float* __restrict__ sa_bk, const float* __restrict__ sa_bv,
    const float* __restrict__ ca_bq, const float* __restrict__ ca_bk, const float* __restrict__ ca_bv,
    float* __restrict__ sab, float* __restrict__ cab)
{
    const int idx = blockIdx.x * 256 + threadIdx.x;
    const int half = idx / 12288;
    const int r    = idx % 12288;
    const int l    = r / 3072;
    const int pc   = r % 3072;
    const int part = pc >> 10;
    const int c    = pc & 1023;
    const float* src = half == 0 ? (part == 0 ? sa_bq : part == 1 ? sa_bk : sa_bv)
                                 : (part == 0 ? ca_bq : part == 1 ? ca_bk : ca_bv);
    const float v = src[l * 1024 + c] * (part == 0 ? 0.125f : 1.f);
    (half ? cab : sab)[l * 3072 + pc] = v;
}

// ---------------------------------------------------------------------------
extern "C" void kernel_launch(void* const* d_in, const int* in_sizes, int n_in,
                              void* d_out, int out_size, void* d_ws, size_t ws_size,
                              hipStream_t stream)
{
    (void)in_sizes; (void)n_in; (void)out_size; (void)ws_size;
    const int M  = 4096;
    const int Dm = 1024;
    const size_t DD = (size_t)Dm * Dm;

    const float* tgt   = (const float*)d_in[0];
    const float* mem   = (const float*)d_in[1];
    const float* sa_wq = (const float*)d_in[2];
    const float* sa_wk = (const float*)d_in[3];
    const float* sa_wv = (const float*)d_in[4];
    const float* sa_wo = (const float*)d_in[5];
    const float* sa_bq = (const float*)d_in[6];
    const float* sa_bk = (const float*)d_in[7];
    const float* sa_bv = (const float*)d_in[8];
    const float* sa_bo = (const float*)d_in[9];
    const float* ca_wq = (const float*)d_in[10];
    const float* ca_wk = (const float*)d_in[11];
    const float* ca_wv = (const float*)d_in[12];
    const float* ca_wo = (const float*)d_in[13];
    const float* ca_bq = (const float*)d_in[14];
    const float* ca_bk = (const float*)d_in[15];
    const float* ca_bv = (const float*)d_in[16];
    const float* ca_bo = (const float*)d_in[17];
    const float* w1    = (const float*)d_in[18];
    const float* b1    = (const float*)d_in[19];
    const float* w2    = (const float*)d_in[20];
    const float* b2    = (const float*)d_in[21];
    const float* ln1g  = (const float*)d_in[22];
    const float* ln1b  = (const float*)d_in[23];
    const float* ln2g  = (const float*)d_in[24];
    const float* ln2b  = (const float*)d_in[25];
    const float* ln3g  = (const float*)d_in[26];
    const float* ln3b  = (const float*)d_in[27];
    const float* lnfg  = (const float*)d_in[28];
    const float* lnfb  = (const float*)d_in[29];

    char* p = (char*)d_ws;
    unsigned short* x_b    = (unsigned short*)p; p += (size_t)M * Dm * 2;       //  8.39 MB (residual + GEMM input)
    unsigned short* mem_b  = (unsigned short*)p; p += (size_t)M * Dm * 2;
    unsigned short* qkv_b  = (unsigned short*)p; p += (size_t)M * 3072 * 2;     // 25.17 MB
    unsigned short* cakv_b = (unsigned short*)p; p += (size_t)M * 2048 * 2;     // 16.78 MB
    unsigned short* caq_b  = (unsigned short*)p; p += (size_t)M * Dm * 2;
    unsigned short* ao_b   = (unsigned short*)p; p += (size_t)M * Dm * 2;
    unsigned short* wpack  = (unsigned short*)p; p += 16 * DD * 2;              // 33.55 MB
    float*          sab    = (float*)p;          p += 4 * 3072 * 4;
    float*          cab    = (float*)p;          p += 4 * 3072 * 4;
    unsigned short* h_b    = qkv_b;                                             // [4096][4096] bf16
    // bf16 split-K partials (8.39 MB each, live only gemm -> ln_red2):
    unsigned short* parA   = qkv_b;                                             // dead Q/K/V
    unsigned short* parB   = cakv_b;                                            // dead ca K/V
    unsigned short* par0   = (unsigned short*)((char*)qkv_b + (size_t)M * 4096 * 2); // cakv tail
    unsigned short* par1   = wpack;                                             // dead packed sa-qkv

    dim3 blk(256), blkA(128);

    cvt2_bf16<<<8192, blk, 0, stream>>>(tgt, mem, x_b, mem_b, M * Dm);
    pack_bias<<<96, blk, 0, stream>>>(sa_bq, sa_bk, sa_bv, ca_bq, ca_bk, ca_bv, sab, cab);

    for (int i = 0; i < 4; ++i) {
        pack_layer_w<<<16384, blk, 0, stream>>>(sa_wq, sa_wk, sa_wv, ca_wq, ca_wk, ca_wv,
                                                sa_wo, ca_wo, w1, w2, wpack, i);
        // --- self-attention ---
        gemm128<<<dim3(24, 32, 1), blk, 0, stream>>>(x_b, wpack, sab + i * 3072,
            qkv_b, nullptr, nullptr, 3072, 1024, 1024, 0);
        attn_fused<<<512, blkA, 0, stream>>>(qkv_b, 3072, qkv_b + 1024, 3072, qkv_b + 2048, 3072, ao_b, 1);
        gemm128<<<dim3(8, 32, 2), blk, 0, stream>>>(ao_b, wpack + 6 * DD, nullptr,
            nullptr, parA, parB, 1024, 1024, 512, 3);
        ln_red2<<<1024, blk, 0, stream>>>(parA, parB, sa_bo + i * Dm, x_b,
            ln1g + i * Dm, ln1b + i * Dm, x_b);
        // --- cross-attention (caQ + caKV in ONE dispatch) ---
        gemm128_ca<<<dim3(24, 32, 1), blk, 0, stream>>>(x_b, mem_b,
            wpack + 3 * DD, wpack + 4 * DD,
            cab + i * 3072, cab + i * 3072 + 1024,
            caq_b, cakv_b, 1024, 1024);
        attn_fused<<<512, blkA, 0, stream>>>(caq_b, 1024, cakv_b, 2048, cakv_b + 1024, 2048, ao_b, 0);
        gemm128<<<dim3(8, 32, 2), blk, 0, stream>>>(ao_b, wpack + 7 * DD, nullptr,
            nullptr, parA, parB, 1024, 1024, 512, 3);
        ln_red2<<<1024, blk, 0, stream>>>(parA, parB, ca_bo + i * Dm, x_b,
            ln2g + i * Dm, ln2b + i * Dm, x_b);
        // --- FFN ---
        gemm128<<<dim3(32, 32, 1), blk, 0, stream>>>(x_b, wpack + 8 * DD, b1 + i * 4096,
            h_b, nullptr, nullptr, 4096, 1024, 1024, 1);
        gemm128<<<dim3(8, 32, 2), blk, 0, stream>>>(h_b, wpack + 12 * DD, nullptr,
            nullptr, par0, par1, 1024, 4096, 2048, 3);
        ln_red2<<<1024, blk, 0, stream>>>(par0, par1, b2 + i * Dm, x_b,
            ln3g + i * Dm, ln3b + i * Dm, x_b);
    }
    ln_final<<<1024, blk, 0, stream>>>(x_b, lnfg, lnfb, (float*)d_out);
}

// Round 13
// 1232.256 us; speedup vs baseline: 1.6868x; 1.0090x over previous
//
#include <hip/hip_runtime.h>

// ---------------------------------------------------------------------------
// 4-layer transformer decoder, bf16 MFMA implementation (round 13).
// = round 12 (1243 us) + G13 vectorization of the memory-bound tail:
//   ln_red2 / ln_final with 16B bf16 loads+stores, pack_layer_w 8 elem/thread,
//   cvt+bias merged into one prep dispatch. GEMM/attention untouched (r8 core:
//   128x128, BK=32, 2-buf issue-early, 4 blocks/CU, slot-XOR + XCD swizzle,
//   bf16 split-K partials, bf16 residual stream).
// ---------------------------------------------------------------------------

typedef __attribute__((ext_vector_type(4))) float f32x4;
typedef __attribute__((ext_vector_type(8))) short bf16x8;
typedef __attribute__((ext_vector_type(4))) unsigned short u16x4;
typedef __attribute__((ext_vector_type(8))) unsigned short u16x8;
typedef __attribute__((ext_vector_type(4))) unsigned int   u32x4;

__device__ __forceinline__ unsigned short f2bf(float f) {
    unsigned int u = __builtin_bit_cast(unsigned int, f);
    u += 0x7fffu + ((u >> 16) & 1u);   // RNE
    return (unsigned short)(u >> 16);
}
__device__ __forceinline__ float bf2f(unsigned short u) {
    return __builtin_bit_cast(float, (unsigned int)u << 16);
}

__device__ __forceinline__ void gll16(const unsigned short* g, unsigned short* l) {
    auto* gp = reinterpret_cast<const __attribute__((address_space(1))) unsigned int*>(
        reinterpret_cast<uintptr_t>(g));
    auto* lp = reinterpret_cast<__attribute__((address_space(3))) unsigned int*>(
        reinterpret_cast<uintptr_t>(l));
    __builtin_amdgcn_global_load_lds(gp, lp, 16, 0, 0);
}

// ---------------------------------------------------------------------------
// Shared 128x128 GEMM body (r8-proven).
// mode 0: bf16(acc+bias)  1: bf16(relu(acc+bias))  3: bf16 raw partial -> po
// ---------------------------------------------------------------------------
__device__ __forceinline__ void gemm_body(
    const unsigned short* __restrict__ A,
    const unsigned short* __restrict__ Bw,
    const float* __restrict__ bias,
    unsigned short* __restrict__ outb,
    unsigned short* __restrict__ po,
    int N, int lda, int klen, int mode,
    int m0, int n0, int kz,
    unsigned short (*Al)[128 * 32], unsigned short (*Bl)[128 * 32])
{
    const int tid  = threadIdx.x;
    const int lane = tid & 63;
    const int w    = tid >> 6;
    const int wr   = (w >> 1) * 64;
    const int wc   = (w & 1) * 64;
    const int l15  = lane & 15;
    const int l4   = lane >> 4;

    const int srow = w * 16 + (lane >> 2);
    const int scol = ((lane & 3) ^ ((srow >> 1) & 3)) * 8;
    const unsigned short* ag = A  + (size_t)(m0 + srow) * lda + kz + scol;
    const unsigned short* bg = Bw + (size_t)(n0 + srow) * lda + kz + scol;
    const size_t jstep = (size_t)64 * lda;
    const int lbase = (w * 16) * 32;

    int aoff[4], boff[4];
    #pragma unroll
    for (int i = 0; i < 4; ++i) {
        const int ra = wr + i * 16 + l15;
        const int rb = wc + i * 16 + l15;
        aoff[i] = ra * 32 + ((l4 ^ ((ra >> 1) & 3)) * 8);
        boff[i] = rb * 32 + ((l4 ^ ((rb >> 1) & 3)) * 8);
    }

    f32x4 acc[4][4];
    #pragma unroll
    for (int mi = 0; mi < 4; ++mi)
        #pragma unroll
        for (int ni = 0; ni < 4; ++ni)
            acc[mi][ni] = (f32x4){0.f, 0.f, 0.f, 0.f};

    #pragma unroll
    for (int j = 0; j < 2; ++j) {
        gll16(ag + j * jstep, &Al[0][lbase + j * 64 * 32]);
        gll16(bg + j * jstep, &Bl[0][lbase + j * 64 * 32]);
    }
    __syncthreads();

    const int nt = klen >> 5;
    int cur = 0;
    for (int t = 0; t < nt; ++t) {
        if (t + 1 < nt) {
            ag += 32; bg += 32;
            #pragma unroll
            for (int j = 0; j < 2; ++j) {
                gll16(ag + j * jstep, &Al[cur ^ 1][lbase + j * 64 * 32]);
                gll16(bg + j * jstep, &Bl[cur ^ 1][lbase + j * 64 * 32]);
            }
        }
        const unsigned short* ac = &Al[cur][0];
        const unsigned short* bc = &Bl[cur][0];
        bf16x8 af[4], bf[4];
        #pragma unroll
        for (int i = 0; i < 4; ++i) af[i] = *reinterpret_cast<const bf16x8*>(&ac[aoff[i]]);
        #pragma unroll
        for (int i = 0; i < 4; ++i) bf[i] = *reinterpret_cast<const bf16x8*>(&bc[boff[i]]);
        #pragma unroll
        for (int mi = 0; mi < 4; ++mi)
            #pragma unroll
            for (int ni = 0; ni < 4; ++ni)
                acc[mi][ni] = __builtin_amdgcn_mfma_f32_16x16x32_bf16(af[mi], bf[ni], acc[mi][ni], 0, 0, 0);
        __syncthreads();
        cur ^= 1;
    }

    // epilogue: C/D layout col = lane&15, row = (lane>>4)*4 + r
    #pragma unroll
    for (int mi = 0; mi < 4; ++mi) {
        #pragma unroll
        for (int ni = 0; ni < 4; ++ni) {
            const int col = n0 + wc + ni * 16 + l15;
            const float bs = (mode == 3) ? 0.f : bias[col];
            #pragma unroll
            for (int r = 0; r < 4; ++r) {
                const int row = m0 + wr + mi * 16 + l4 * 4 + r;
                const float val = acc[mi][ni][r] + bs;
                if (mode == 0)      outb[(size_t)row * N + col] = f2bf(val);
                else if (mode == 1) outb[(size_t)row * N + col] = f2bf(fmaxf(val, 0.f));
                else                po[(size_t)row * N + col] = f2bf(val);
            }
        }
    }
}

// gemm128: XCD band swizzle (gy == 32, nwg % 8 == 0); split-K via blockIdx.z
__global__ __launch_bounds__(256, 4) void gemm128(
    const unsigned short* __restrict__ A,
    const unsigned short* __restrict__ Bw,
    const float* __restrict__ bias,
    unsigned short* __restrict__ outb,
    unsigned short* __restrict__ pb0,
    unsigned short* __restrict__ pb1,
    int N, int lda, int klen, int mode)
{
    __shared__ unsigned short Al[2][128 * 32];
    __shared__ unsigned short Bl[2][128 * 32];
    const int gx   = gridDim.x;
    const int orig = blockIdx.y * gx + blockIdx.x;
    const int xcd  = orig & 7;
    const int lin  = orig >> 3;
    const int m0   = (xcd * 4 + (lin & 3)) * 128;
    const int n0   = (lin >> 2) * 128;
    const int kz   = blockIdx.z * klen;
    unsigned short* po = (blockIdx.z == 0) ? pb0 : pb1;
    gemm_body(A, Bw, bias, outb, po, N, lda, klen, mode, m0, n0, kz, Al, Bl);
}

// gemm128_ca: dual-job dispatch (caQ N=1024 | caKV N=2048), both mode 0.
__global__ __launch_bounds__(256, 4) void gemm128_ca(
    const unsigned short* __restrict__ A0, const unsigned short* __restrict__ A1,
    const unsigned short* __restrict__ B0, const unsigned short* __restrict__ B1,
    const float* __restrict__ bias0, const float* __restrict__ bias1,
    unsigned short* __restrict__ out0, unsigned short* __restrict__ out1,
    int lda, int klen)
{
    __shared__ unsigned short Al[2][128 * 32];
    __shared__ unsigned short Bl[2][128 * 32];
    const int grp = (blockIdx.x >= 8);
    const int bx  = blockIdx.x - (grp ? 8 : 0);
    const int lgx = grp ? 16 : 8;
    const int orig = blockIdx.y * lgx + bx;
    const int xcd  = orig & 7;
    const int lin  = orig >> 3;
    const int m0   = (xcd * 4 + (lin & 3)) * 128;
    const int n0   = (lin >> 2) * 128;
    gemm_body(grp ? A1 : A0, grp ? B1 : B0, grp ? bias1 : bias0,
              grp ? out1 : out0, nullptr, grp ? 2048 : 1024, lda, klen, 0,
              m0, n0, 0, Al, Bl);
}

// ---------------------------------------------------------------------------
// Fused attention: 128-thread blocks (2 waves), grid 512 = (n,h,thalf).
// Causal: wave-uniform tile-skip in QK and PV.
// ---------------------------------------------------------------------------
__global__ __launch_bounds__(128) void attn_fused(
    const unsigned short* __restrict__ Q, int qs,
    const unsigned short* __restrict__ Kb, int ks_,
    const unsigned short* __restrict__ Vb, int vs,
    unsigned short* __restrict__ O,
    int causal)
{
    __shared__ unsigned short Kl[8][256][8];
    __shared__ unsigned short Vt[32][64][8];
    __shared__ unsigned short Pl[2][32][16][8];
    const int tid   = threadIdx.x;
    const int lane  = tid & 63;
    const int w     = tid >> 6;
    const int bxi   = blockIdx.x;
    const int n     = bxi >> 5;
    const int h     = (bxi >> 1) & 15;
    const int thalf = bxi & 1;
    const int l15   = lane & 15;
    const int l4    = lane >> 4;
    const size_t hoff = (size_t)h * 64;

    #pragma unroll
    for (int i = 0; i < 16; ++i) {
        const int e = i * 128 + tid;
        const int s = e >> 3;
        const int c = e & 7;
        u32x4 kv = *reinterpret_cast<const u32x4*>(&Kb[((size_t)s * 16 + n) * ks_ + hoff + c * 8]);
        *reinterpret_cast<u32x4*>(&Kl[c][s][0]) = kv;
        u32x4 vv = *reinterpret_cast<const u32x4*>(&Vb[((size_t)s * 16 + n) * vs + hoff + c * 8]);
        const unsigned short* ve = reinterpret_cast<const unsigned short*>(&vv);
        #pragma unroll
        for (int j = 0; j < 8; ++j)
            Vt[s >> 3][c * 8 + j][s & 7] = ve[j];
    }
    __syncthreads();

    for (int ch = 0; ch < 4; ++ch) {
        const int t0 = thalf * 128 + w * 64 + ch * 16;
        bf16x8 qa[2];
        #pragma unroll
        for (int ks = 0; ks < 2; ++ks)
            qa[ks] = *reinterpret_cast<const bf16x8*>(
                &Q[((size_t)(t0 + l15) * 16 + n) * qs + hoff + ks * 32 + l4 * 8]);

        f32x4 sc[16];
        #pragma unroll
        for (int st = 0; st < 16; ++st) {
            if (causal && st * 16 > t0 + 15) {
                sc[st] = (f32x4){-1e9f, -1e9f, -1e9f, -1e9f};
                continue;
            }
            f32x4 a = (f32x4){0.f, 0.f, 0.f, 0.f};
            #pragma unroll
            for (int ks = 0; ks < 2; ++ks) {
                bf16x8 kf = *reinterpret_cast<const bf16x8*>(&Kl[ks * 4 + l4][st * 16 + l15][0]);
                a = __builtin_amdgcn_mfma_f32_16x16x32_bf16(qa[ks], kf, a, 0, 0, 0);
            }
            sc[st] = a;
        }
        if (causal) {
            #pragma unroll
            for (int st = 0; st < 16; ++st) {
                const int sg = st * 16 + l15;
                #pragma unroll
                for (int r = 0; r < 4; ++r) {
                    const int tg = t0 + l4 * 4 + r;
                    if (sg > tg) sc[st][r] = -1e9f;
                }
            }
        }
        #pragma unroll
        for (int r = 0; r < 4; ++r) {
            float mx = -3.0e38f;
            #pragma unroll
            for (int st = 0; st < 16; ++st) mx = fmaxf(mx, sc[st][r]);
            #pragma unroll
            for (int dd = 1; dd < 16; dd <<= 1) mx = fmaxf(mx, __shfl_xor(mx, dd, 64));
            float sum = 0.f;
            #pragma unroll
            for (int st = 0; st < 16; ++st) {
                const float e = __expf(sc[st][r] - mx);
                sc[st][r] = e;
                sum += e;
            }
            #pragma unroll
            for (int dd = 1; dd < 16; dd <<= 1) sum += __shfl_xor(sum, dd, 64);
            const float inv = 1.f / sum;
            const int rl = l4 * 4 + r;
            #pragma unroll
            for (int st = 0; st < 16; ++st) {
                const int sg = st * 16 + l15;
                Pl[w][sg >> 3][rl][sg & 7] = f2bf(sc[st][r] * inv);
            }
        }
        f32x4 oacc[4];
        #pragma unroll
        for (int dt = 0; dt < 4; ++dt) oacc[dt] = (f32x4){0.f, 0.f, 0.f, 0.f};
        #pragma unroll
        for (int kt = 0; kt < 8; ++kt) {
            if (causal && kt * 32 > t0 + 15) continue;
            bf16x8 pa = *reinterpret_cast<const bf16x8*>(&Pl[w][kt * 4 + l4][l15][0]);
            #pragma unroll
            for (int dt = 0; dt < 4; ++dt) {
                bf16x8 vf = *reinterpret_cast<const bf16x8*>(&Vt[kt * 4 + l4][dt * 16 + l15][0]);
                oacc[dt] = __builtin_amdgcn_mfma_f32_16x16x32_bf16(pa, vf, oacc[dt], 0, 0, 0);
            }
        }
        #pragma unroll
        for (int dt = 0; dt < 4; ++dt)
            #pragma unroll
            for (int r = 0; r < 4; ++r)
                O[((size_t)(t0 + l4 * 4 + r) * 16 + n) * 1024 + hoff + dt * 16 + l15] = f2bf(oacc[dt][r]);
    }
}

// ---------------------------------------------------------------------------
// Wide LayerNorm helpers: one wave per row, 2 passes of 8 cols/lane, all
// bf16 traffic as u16x8 (16 B/lane — G13).
// ---------------------------------------------------------------------------
__device__ __forceinline__ void ln_wide_finish(
    float (&v)[2][8], int row, int lane,
    const float* __restrict__ g, const float* __restrict__ b,
    float* __restrict__ outf, unsigned short* __restrict__ outb)
{
    float s = 0.f;
    #pragma unroll
    for (int ps = 0; ps < 2; ++ps)
        #pragma unroll
        for (int j = 0; j < 8; ++j) s += v[ps][j];
    #pragma unroll
    for (int dd = 1; dd < 64; dd <<= 1) s += __shfl_xor(s, dd, 64);
    const float mu = s * (1.f / 1024.f);
    float q = 0.f;
    #pragma unroll
    for (int ps = 0; ps < 2; ++ps)
        #pragma unroll
        for (int j = 0; j < 8; ++j) { const float d0 = v[ps][j] - mu; q += d0 * d0; }
    #pragma unroll
    for (int dd = 1; dd < 64; dd <<= 1) q += __shfl_xor(q, dd, 64);
    const float rstd = rsqrtf(q * (1.f / 1024.f) + 1e-5f);
    #pragma unroll
    for (int ps = 0; ps < 2; ++ps) {
        const int col = ps * 512 + lane * 8;
        f32x4 g0 = *reinterpret_cast<const f32x4*>(&g[col]);
        f32x4 g1 = *reinterpret_cast<const f32x4*>(&g[col + 4]);
        f32x4 b0 = *reinterpret_cast<const f32x4*>(&b[col]);
        f32x4 b1 = *reinterpret_cast<const f32x4*>(&b[col + 4]);
        float y[8];
        #pragma unroll
        for (int j = 0; j < 8; ++j) {
            const float gg = (j < 4) ? g0[j] : g1[j - 4];
            const float bb = (j < 4) ? b0[j] : b1[j - 4];
            y[j] = (v[ps][j] - mu) * rstd * gg + bb;
        }
        const size_t o = (size_t)row * 1024 + col;
        if (outb) {
            u16x8 pk;
            #pragma unroll
            for (int j = 0; j < 8; ++j) pk[j] = f2bf(y[j]);
            *reinterpret_cast<u16x8*>(&outb[o]) = pk;
        }
        if (outf) {
            f32x4 y0, y1;
            #pragma unroll
            for (int j = 0; j < 4; ++j) { y0[j] = y[j]; y1[j] = y[j + 4]; }
            *reinterpret_cast<f32x4*>(&outf[o]) = y0;
            *reinterpret_cast<f32x4*>(&outf[o + 4]) = y1;
        }
    }
}

// z = bf16(p0) + bf16(p1) + bias + bf16(resid); LN -> bf16 xb (resid may alias xb)
__global__ __launch_bounds__(256) void ln_red2(
    const unsigned short* __restrict__ p0, const unsigned short* __restrict__ p1,
    const float* __restrict__ bias, const unsigned short* __restrict__ resid,
    const float* __restrict__ g, const float* __restrict__ b,
    unsigned short* __restrict__ xb)
{
    const int row  = blockIdx.x * 4 + (threadIdx.x >> 6);
    const int lane = threadIdx.x & 63;
    float v[2][8];
    #pragma unroll
    for (int ps = 0; ps < 2; ++ps) {
        const int col = ps * 512 + lane * 8;
        const size_t o = (size_t)row * 1024 + col;
        u16x8 a0 = *reinterpret_cast<const u16x8*>(&p0[o]);
        u16x8 a1 = *reinterpret_cast<const u16x8*>(&p1[o]);
        u16x8 rs = *reinterpret_cast<const u16x8*>(&resid[o]);
        f32x4 b0 = *reinterpret_cast<const f32x4*>(&bias[col]);
        f32x4 b1 = *reinterpret_cast<const f32x4*>(&bias[col + 4]);
        #pragma unroll
        for (int j = 0; j < 8; ++j) {
            const float bs = (j < 4) ? b0[j] : b1[j - 4];
            v[ps][j] = bf2f(a0[j]) + bf2f(a1[j]) + bs + bf2f(rs[j]);
        }
    }
    ln_wide_finish(v, row, lane, g, b, nullptr, xb);
}

// final LN: bf16 input -> fp32 output
__global__ __launch_bounds__(256) void ln_final(
    const unsigned short* __restrict__ z, const float* __restrict__ g,
    const float* __restrict__ b, float* __restrict__ out)
{
    const int row  = blockIdx.x * 4 + (threadIdx.x >> 6);
    const int lane = threadIdx.x & 63;
    float v[2][8];
    #pragma unroll
    for (int ps = 0; ps < 2; ++ps) {
        const size_t o = (size_t)row * 1024 + ps * 512 + lane * 8;
        u16x8 zz = *reinterpret_cast<const u16x8*>(&z[o]);
        #pragma unroll
        for (int j = 0; j < 8; ++j) v[ps][j] = bf2f(zz[j]);
    }
    ln_wide_finish(v, row, lane, g, b, out, nullptr);
}

// ---------------------------------------------------------------------------
// prep: blocks [0,4096) convert tgt+mem fp32->bf16 (8 elem/thread);
//       blocks [4096,4192) pack prescaled fp32 biases.
// ---------------------------------------------------------------------------
__global__ __launch_bounds__(256) void prep(
    const float* __restrict__ tgt, const float* __restrict__ mem,
    unsigned short* __restrict__ x_b, unsigned short* __restrict__ mem_b,
    const float* __restrict__ sa_bq, const float* __restrict__ sa_bk, const float* __restrict__ sa_bv,
    const float* __restrict__ ca_bq, const float* __restrict__ ca_bk, const float* __restrict__ ca_bv,
    float* __restrict__ sab, float* __restrict__ cab)
{
    const int n0 = 4096 * 1024;          // elems per input
    if (blockIdx.x < 4096) {
        const int i = (blockIdx.x * 256 + threadIdx.x) * 8;
        const float* src = (i < n0) ? tgt : mem;
        unsigned short* dst = (i < n0) ? x_b : mem_b;
        const int off = (i < n0) ? i : i - n0;
        f32x4 v0 = *reinterpret_cast<const f32x4*>(&src[off]);
        f32x4 v1 = *reinterpret_cast<const f32x4*>(&src[off + 4]);
        u16x8 pk;
        #pragma unroll
        for (int j = 0; j < 4; ++j) { pk[j] = f2bf(v0[j]); pk[j + 4] = f2bf(v1[j]); }
        *reinterpret_cast<u16x8*>(&dst[off]) = pk;
    } else {
        const int idx = (blockIdx.x - 4096) * 256 + threadIdx.x;   // < 24576
        const int half = idx / 12288;
        const int r    = idx % 12288;
        const int l    = r / 3072;
        const int pc   = r % 3072;
        const int part = pc >> 10;
        const int c    = pc & 1023;
        const float* src = half == 0 ? (part == 0 ? sa_bq : part == 1 ? sa_bk : sa_bv)
                                     : (part == 0 ? ca_bq : part == 1 ? ca_bk : ca_bv);
        const float v = src[l * 1024 + c] * (part == 0 ? 0.125f : 1.f);
        (half ? cab : sab)[l * 3072 + pc] = v;
    }
}

// ---------------------------------------------------------------------------
// Per-layer weight pack (fp32->bf16, Q-scale folded), 8 elems/thread:
//   [0,3DD) sa qkv  [3DD,6DD) ca qkv  [6DD,7DD) sa_wo  [7DD,8DD) ca_wo
//   [8DD,12DD) w1   [12DD,16DD) w2
// ---------------------------------------------------------------------------
__global__ __launch_bounds__(256) void pack_layer_w(
    const float* __restrict__ sa_wq, const float* __restrict__ sa_wk, const float* __restrict__ sa_wv,
    const float* __restrict__ ca_wq, const float* __restrict__ ca_wk, const float* __restrict__ ca_wv,
    const float* __restrict__ sa_wo, const float* __restrict__ ca_wo,
    const float* __restrict__ w1,   const float* __restrict__ w2,
    unsigned short* __restrict__ dst, int layer)
{
    const size_t DD = 1024u * 1024u;
    const size_t e  = ((size_t)blockIdx.x * 256 + threadIdx.x) * 8;
    const float* src;
    float scale = 1.f;
    if (e < 3 * DD) {
        const int part = (int)(e / DD);
        src = (part == 0 ? sa_wq : part == 1 ? sa_wk : sa_wv) + layer * DD + (e % DD);
        if (part == 0) scale = 0.125f;
    } else if (e < 6 * DD) {
        const size_t r = e - 3 * DD;
        const int part = (int)(r / DD);
        src = (part == 0 ? ca_wq : part == 1 ? ca_wk : ca_wv) + layer * DD + (r % DD);
        if (part == 0) scale = 0.125f;
    } else if (e < 7 * DD)  { src = sa_wo + layer * DD + (e - 6 * DD); }
    else if (e < 8 * DD)    { src = ca_wo + layer * DD + (e - 7 * DD); }
    else if (e < 12 * DD)   { src = w1 + (size_t)layer * 4 * DD + (e - 8 * DD); }
    else                    { src = w2 + (size_t)layer * 4 * DD + (e - 12 * DD); }
    f32x4 v0 = *reinterpret_cast<const f32x4*>(src);
    f32x4 v1 = *reinterpret_cast<const f32x4*>(src + 4);
    u16x8 pk;
    #pragma unroll
    for (int j = 0; j < 4; ++j) { pk[j] = f2bf(v0[j] * scale); pk[j + 4] = f2bf(v1[j] * scale); }
    *reinterpret_cast<u16x8*>(&dst[e]) = pk;
}

// ---------------------------------------------------------------------------
extern "C" void kernel_launch(void* const* d_in, const int* in_sizes, int n_in,
                              void* d_out, int out_size, void* d_ws, size_t ws_size,
                              hipStream_t stream)
{
    (void)in_sizes; (void)n_in; (void)out_size; (void)ws_size;
    const int M  = 4096;
    const int Dm = 1024;
    const size_t DD = (size_t)Dm * Dm;

    const float* tgt   = (const float*)d_in[0];
    const float* mem   = (const float*)d_in[1];
    const float* sa_wq = (const float*)d_in[2];
    const float* sa_wk = (const float*)d_in[3];
    const float* sa_wv = (const float*)d_in[4];
    const float* sa_wo = (const float*)d_in[5];
    const float* sa_bq = (const float*)d_in[6];
    const float* sa_bk = (const float*)d_in[7];
    const float* sa_bv = (const float*)d_in[8];
    const float* sa_bo = (const float*)d_in[9];
    const float* ca_wq = (const float*)d_in[10];
    const float* ca_wk = (const float*)d_in[11];
    const float* ca_wv = (const float*)d_in[12];
    const float* ca_wo = (const float*)d_in[13];
    const float* ca_bq = (const float*)d_in[14];
    const float* ca_bk = (const float*)d_in[15];
    const float* ca_bv = (const float*)d_in[16];
    const float* ca_bo = (const float*)d_in[17];
    const float* w1    = (const float*)d_in[18];
    const float* b1    = (const float*)d_in[19];
    const float* w2    = (const float*)d_in[20];
    const float* b2    = (const float*)d_in[21];
    const float* ln1g  = (const float*)d_in[22];
    const float* ln1b  = (const float*)d_in[23];
    const float* ln2g  = (const float*)d_in[24];
    const float* ln2b  = (const float*)d_in[25];
    const float* ln3g  = (const float*)d_in[26];
    const float* ln3b  = (const float*)d_in[27];
    const float* lnfg  = (const float*)d_in[28];
    const float* lnfb  = (const float*)d_in[29];

    char* p = (char*)d_ws;
    unsigned short* x_b    = (unsigned short*)p; p += (size_t)M * Dm * 2;       // residual + GEMM input
    unsigned short* mem_b  = (unsigned short*)p; p += (size_t)M * Dm * 2;
    unsigned short* qkv_b  = (unsigned short*)p; p += (size_t)M * 3072 * 2;
    unsigned short* cakv_b = (unsigned short*)p; p += (size_t)M * 2048 * 2;
    unsigned short* caq_b  = (unsigned short*)p; p += (size_t)M * Dm * 2;
    unsigned short* ao_b   = (unsigned short*)p; p += (size_t)M * Dm * 2;
    unsigned short* wpack  = (unsigned short*)p; p += 16 * DD * 2;
    float*          sab    = (float*)p;          p += 4 * 3072 * 4;
    float*          cab    = (float*)p;          p += 4 * 3072 * 4;
    unsigned short* h_b    = qkv_b;                                             // [4096][4096] bf16
    unsigned short* parA   = qkv_b;                                             // dead Q/K/V
    unsigned short* parB   = cakv_b;                                            // dead ca K/V
    unsigned short* par0   = (unsigned short*)((char*)qkv_b + (size_t)M * 4096 * 2); // cakv tail
    unsigned short* par1   = wpack;                                             // dead packed sa-qkv

    dim3 blk(256), blkA(128);

    prep<<<4192, blk, 0, stream>>>(tgt, mem, x_b, mem_b,
        sa_bq, sa_bk, sa_bv, ca_bq, ca_bk, ca_bv, sab, cab);

    for (int i = 0; i < 4; ++i) {
        pack_layer_w<<<8192, blk, 0, stream>>>(sa_wq, sa_wk, sa_wv, ca_wq, ca_wk, ca_wv,
                                               sa_wo, ca_wo, w1, w2, wpack, i);
        // --- self-attention ---
        gemm128<<<dim3(24, 32, 1), blk, 0, stream>>>(x_b, wpack, sab + i * 3072,
            qkv_b, nullptr, nullptr, 3072, 1024, 1024, 0);
        attn_fused<<<512, blkA, 0, stream>>>(qkv_b, 3072, qkv_b + 1024, 3072, qkv_b + 2048, 3072, ao_b, 1);
        gemm128<<<dim3(8, 32, 2), blk, 0, stream>>>(ao_b, wpack + 6 * DD, nullptr,
            nullptr, parA, parB, 1024, 1024, 512, 3);
        ln_red2<<<1024, blk, 0, stream>>>(parA, parB, sa_bo + i * Dm, x_b,
            ln1g + i * Dm, ln1b + i * Dm, x_b);
        // --- cross-attention (caQ + caKV in ONE dispatch) ---
        gemm128_ca<<<dim3(24, 32, 1), blk, 0, stream>>>(x_b, mem_b,
            wpack + 3 * DD, wpack + 4 * DD,
            cab + i * 3072, cab + i * 3072 + 1024,
            caq_b, cakv_b, 1024, 1024);
        attn_fused<<<512, blkA, 0, stream>>>(caq_b, 1024, cakv_b, 2048, cakv_b + 1024, 2048, ao_b, 0);
        gemm128<<<dim3(8, 32, 2), blk, 0, stream>>>(ao_b, wpack + 7 * DD, nullptr,
            nullptr, parA, parB, 1024, 1024, 512, 3);
        ln_red2<<<1024, blk, 0, stream>>>(parA, parB, ca_bo + i * Dm, x_b,
            ln2g + i * Dm, ln2b + i * Dm, x_b);
        // --- FFN ---
        gemm128<<<dim3(32, 32, 1), blk, 0, stream>>>(x_b, wpack + 8 * DD, b1 + i * 4096,
            h_b, nullptr, nullptr, 4096, 1024, 1024, 1);
        gemm128<<<dim3(8, 32, 2), blk, 0, stream>>>(h_b, wpack + 12 * DD, nullptr,
            nullptr, par0, par1, 1024, 4096, 2048, 3);
        ln_red2<<<1024, blk, 0, stream>>>(par0, par1, b2 + i * Dm, x_b,
            ln3g + i * Dm, ln3b + i * Dm, x_b);
    }
    ln_final<<<1024, blk, 0, stream>>>(x_b, lnfg, lnfb, (float*)d_out);
}